// Round 9
// baseline (988.317 us; speedup 1.0000x reference)
//
#include <hip/hip_runtime.h>
#include <hip/hip_bf16.h>

#define DEVI __device__ __forceinline__

using bf16x8 = __attribute__((ext_vector_type(8))) short;   // 8 bf16 in 4 VGPRs (per guide §3)
using f32x4  = __attribute__((ext_vector_type(4))) float;

DEVI unsigned short f2bf(float f) {
    unsigned u = __builtin_bit_cast(unsigned, f);
    return (unsigned short)((u + 0x7FFFu + ((u >> 16) & 1u)) >> 16);
}
DEVI float bf2f(unsigned short h) {
    return __builtin_bit_cast(float, (unsigned)h << 16);
}

DEVI f32x4 mfma16(bf16x8 a, bf16x8 b, f32x4 c) {
    return __builtin_amdgcn_mfma_f32_16x16x32_bf16(a, b, c, 0, 0, 0);
}

// async global->LDS, 16B per lane, LDS dest = wave-uniform base + lane*16 (guide §5)
DEVI void gl16(const void* g, void* l) {
    __builtin_amdgcn_global_load_lds((const __attribute__((address_space(1))) void*)g,
                                     (__attribute__((address_space(3))) void*)l,
                                     16, 0, 0);
}

// ---------------- ALL weight transposes + bf16 cast in ONE launch ----------------
__global__ void k_transpose_all(const float* __restrict__ W1, const float* __restrict__ W2,
                                const float* __restrict__ Wa, const float* __restrict__ Wb,
                                const float* __restrict__ Wd1, const float* __restrict__ Wd2,
                                unsigned short* __restrict__ W1T, unsigned short* __restrict__ W2T,
                                unsigned short* __restrict__ WaT, unsigned short* __restrict__ WbT,
                                unsigned short* __restrict__ Wd1T, unsigned short* __restrict__ Wd2T) {
    long i = (long)blockIdx.x * 256 + threadIdx.x;
    if (i < 524288) {                      // W1T: [512][1024] <- W1 [1024][512]
        int nn = (int)(i >> 10), kk = (int)(i & 1023);
        W1T[i] = f2bf(W1[(long)kk * 512 + nn]);
        return;
    }
    i -= 524288;
    if (i < 131072) {                      // W2T: [256][512] <- W2 [512][256]
        int nn = (int)(i >> 9), kk = (int)(i & 511);
        W2T[i] = f2bf(W2[(long)kk * 256 + nn]);
        return;
    }
    i -= 131072;
    if (i < 196608) {                      // WaT: 3 x [256][256]
        int li = (int)(i & 65535), layer = (int)(i >> 16);
        int nn = li >> 8, kk = li & 255;
        WaT[i] = f2bf(Wa[(long)layer * 65536 + (long)kk * 256 + nn]);
        return;
    }
    i -= 196608;
    if (i < 196608) {                      // WbT: 3 x [256][256]
        int li = (int)(i & 65535), layer = (int)(i >> 16);
        int nn = li >> 8, kk = li & 255;
        WbT[i] = f2bf(Wb[(long)layer * 65536 + (long)kk * 256 + nn]);
        return;
    }
    i -= 196608;
    if (i < 131072) {                      // Wd1T: [512][256] <- Wd1 [256][512]
        int nn = (int)(i >> 8), kk = (int)(i & 255);
        Wd1T[i] = f2bf(Wd1[(long)kk * 512 + nn]);
        return;
    }
    i -= 131072;
    if (i < 524288) {                      // Wd2T: [1024][512] <- Wd2 [512][1024]
        int nn = (int)(i >> 9), kk = (int)(i & 511);
        Wd2T[i] = f2bf(Wd2[(long)kk * 1024 + nn]);
    }
}

// ---------------- CSR build ----------------
__global__ void k_zero_i32(int* p, int n) {
    int i = blockIdx.x * 256 + threadIdx.x;
    if (i < n) p[i] = 0;
}
__global__ void k_hist(const int* __restrict__ dst, int E, int* __restrict__ deg) {
    int i = blockIdx.x * 256 + threadIdx.x;
    if (i < E) atomicAdd(&deg[dst[i]], 1);
}
__global__ __launch_bounds__(1024)
void k_scan1(const int* __restrict__ deg, int* __restrict__ rp, int* __restrict__ bsum, int n) {
    __shared__ int sh[1024];
    int t = threadIdx.x;
    int i = blockIdx.x * 1024 + t;
    int v = (i < n) ? deg[i] : 0;
    sh[t] = v;
    __syncthreads();
    for (int off = 1; off < 1024; off <<= 1) {
        int y = (t >= off) ? sh[t - off] : 0;
        __syncthreads();
        sh[t] += y;
        __syncthreads();
    }
    if (i < n) rp[i] = sh[t] - v;            // exclusive within block
    if (t == 1023) bsum[blockIdx.x] = sh[1023];
}
__global__ __launch_bounds__(64)
void k_scan2(const int* __restrict__ bsum, int* __restrict__ boff, int nb) {  // nb <= 64
    int lane = threadIdx.x;
    int v = (lane < nb) ? bsum[lane] : 0;
    int x = v;
    for (int off = 1; off < 64; off <<= 1) {
        int y = __shfl_up(x, off);
        if (lane >= off) x += y;
    }
    if (lane < nb) boff[lane] = x - v;
}
__global__ void k_scan3(int* __restrict__ rp, const int* __restrict__ boff,
                        int* __restrict__ cur, int n, int E) {
    int i = blockIdx.x * 256 + threadIdx.x;
    if (i < n) {
        int v = rp[i] + boff[i >> 10];
        rp[i] = v;
        cur[i] = v;
    }
    if (i == 0) rp[n] = E;
}
__global__ void k_fill(const int* __restrict__ src, const int* __restrict__ dst, int E,
                       int* __restrict__ cur, int* __restrict__ esrc) {
    int i = blockIdx.x * 256 + threadIdx.x;
    if (i < E) {
        int d = dst[i];
        int p = atomicAdd(&cur[d], 1);
        esrc[p] = src[i];
    }
}

// ---------------- LayerNorm kernels ----------------
__global__ __launch_bounds__(256)
void k_ln1024_in(const float* __restrict__ x, const float* __restrict__ g,
                 const float* __restrict__ b, unsigned short* __restrict__ out) {
    const long row = blockIdx.x;
    const int tid = threadIdx.x, lane = tid & 63, wid = tid >> 6;
    float4 v = ((const float4*)(x + row * 1024))[tid];
    float s = v.x + v.y + v.z + v.w;
    float s2 = v.x * v.x + v.y * v.y + v.z * v.z + v.w * v.w;
    for (int off = 1; off < 64; off <<= 1) { s += __shfl_xor(s, off); s2 += __shfl_xor(s2, off); }
    __shared__ float red[8];
    if (lane == 0) { red[wid] = s; red[4 + wid] = s2; }
    __syncthreads();
    s = red[0] + red[1] + red[2] + red[3];
    s2 = red[4] + red[5] + red[6] + red[7];
    float m = s * (1.f / 1024.f);
    float var = s2 * (1.f / 1024.f) - m * m;
    float inv = rsqrtf(var + 1e-5f);
    float4 gv = ((const float4*)g)[tid];
    float4 bv = ((const float4*)b)[tid];
    ushort4 o = make_ushort4(f2bf((v.x - m) * inv * gv.x + bv.x),
                             f2bf((v.y - m) * inv * gv.y + bv.y),
                             f2bf((v.z - m) * inv * gv.z + bv.z),
                             f2bf((v.w - m) * inv * gv.w + bv.w));
    ((ushort4*)(out + row * 1024))[tid] = o;
}

__global__ __launch_bounds__(256)
void k_ln1024_out(const float* __restrict__ x, const unsigned short* __restrict__ delta,
                  const float* __restrict__ g, const float* __restrict__ b,
                  float* __restrict__ out) {
    const long row = blockIdx.x;
    const int tid = threadIdx.x, lane = tid & 63, wid = tid >> 6;
    float4 xv = ((const float4*)(x + row * 1024))[tid];
    ushort4 dv = ((const ushort4*)(delta + row * 1024))[tid];
    float4 v;
    v.x = xv.x + bf2f(dv.x);
    v.y = xv.y + bf2f(dv.y);
    v.z = xv.z + bf2f(dv.z);
    v.w = xv.w + bf2f(dv.w);
    float s = v.x + v.y + v.z + v.w;
    float s2 = v.x * v.x + v.y * v.y + v.z * v.z + v.w * v.w;
    for (int off = 1; off < 64; off <<= 1) { s += __shfl_xor(s, off); s2 += __shfl_xor(s2, off); }
    __shared__ float red[8];
    if (lane == 0) { red[wid] = s; red[4 + wid] = s2; }
    __syncthreads();
    s = red[0] + red[1] + red[2] + red[3];
    s2 = red[4] + red[5] + red[6] + red[7];
    float m = s * (1.f / 1024.f);
    float var = s2 * (1.f / 1024.f) - m * m;
    float inv = rsqrtf(var + 1e-5f);
    float4 gv = ((const float4*)g)[tid];
    float4 bv = ((const float4*)b)[tid];
    float4 o;
    o.x = (v.x - m) * inv * gv.x + bv.x;
    o.y = (v.y - m) * inv * gv.y + bv.y;
    o.z = (v.z - m) * inv * gv.z + bv.z;
    o.w = (v.w - m) * inv * gv.w + bv.w;
    ((float4*)(out + row * 1024))[tid] = o;
}

// ---------------- aggregation: z[dst] = h[dst] + sum_{src in-edges} h[src] ----------------
__global__ __launch_bounds__(256)
void k_agg(const float* __restrict__ hf, const unsigned short* __restrict__ hb,
           const int* __restrict__ rp, const int* __restrict__ esrc,
           unsigned short* __restrict__ z, int n) {
    int node = blockIdx.x * 4 + (threadIdx.x >> 6);
    if (node >= n) return;
    int lane = threadIdx.x & 63;
    float4 sv = ((const float4*)(hf + (long)node * 256))[lane];
    float a0 = sv.x, a1 = sv.y, a2 = sv.z, a3 = sv.w;
    int beg = rp[node], end = rp[node + 1];
    int e = beg;
    for (; e + 4 <= end; e += 4) {
        int s0 = esrc[e], s1 = esrc[e + 1], s2 = esrc[e + 2], s3 = esrc[e + 3];
        ushort4 v0 = ((const ushort4*)(hb + (long)s0 * 256))[lane];
        ushort4 v1 = ((const ushort4*)(hb + (long)s1 * 256))[lane];
        ushort4 v2 = ((const ushort4*)(hb + (long)s2 * 256))[lane];
        ushort4 v3 = ((const ushort4*)(hb + (long)s3 * 256))[lane];
        a0 += bf2f(v0.x) + bf2f(v1.x) + bf2f(v2.x) + bf2f(v3.x);
        a1 += bf2f(v0.y) + bf2f(v1.y) + bf2f(v2.y) + bf2f(v3.y);
        a2 += bf2f(v0.z) + bf2f(v1.z) + bf2f(v2.z) + bf2f(v3.z);
        a3 += bf2f(v0.w) + bf2f(v1.w) + bf2f(v2.w) + bf2f(v3.w);
    }
    for (; e < end; ++e) {
        int s = esrc[e];
        ushort4 hv = ((const ushort4*)(hb + (long)s * 256))[lane];
        a0 += bf2f(hv.x);
        a1 += bf2f(hv.y);
        a2 += bf2f(hv.z);
        a3 += bf2f(hv.w);
    }
    ushort4 o = make_ushort4(f2bf(a0), f2bf(a1), f2bf(a2), f2bf(a3));
    ((ushort4*)(z + (long)node * 256))[lane] = o;
}

// ---------------- bf16 MFMA GEMM: 128x128 tile (r3 schedule, proven) ----------------
template <int RELU, int WB, int WF>
__global__ __launch_bounds__(256)
void k_gemm(const unsigned short* __restrict__ A, const unsigned short* __restrict__ WT,
            const float* __restrict__ bias, int M, int K, int Nc,
            unsigned short* __restrict__ outb, float* __restrict__ outf) {
    __shared__ __align__(16) unsigned short lds_a[3 * 4096];
    __shared__ __align__(16) unsigned short lds_b[3 * 4096];
    const int tid = threadIdx.x;
    const int wid = tid >> 6, lane = tid & 63;

    const int nwg = gridDim.x;
    const int q = nwg >> 3, r8 = nwg & 7;
    const int xcd = blockIdx.x & 7, sl = blockIdx.x >> 3;
    const int bid = (xcd < r8 ? xcd * (q + 1) : r8 * (q + 1) + (xcd - r8) * q) + sl;

    const int ntN = Nc >> 7;
    const int tM = bid / ntN, tN = bid - tM * ntN;
    const long row0 = (long)tM * 128;
    const int col0 = tN << 7;
    const int wr = wid >> 1, wc = wid & 1;

    const int sr = tid >> 2;
    const int sc = (((tid & 3) ^ ((sr >> 2) & 3)) << 3);
    long ra0 = row0 + sr;       if (ra0 > (long)M - 1) ra0 = M - 1;
    long ra1 = row0 + sr + 64;  if (ra1 > (long)M - 1) ra1 = M - 1;
    const unsigned short* pa0 = A + ra0 * K + sc;
    const unsigned short* pa1 = A + ra1 * K + sc;
    const unsigned short* pb0 = WT + (long)(col0 + sr) * K + sc;
    const unsigned short* pb1 = WT + (long)(col0 + sr + 64) * K + sc;

    f32x4 zero4 = {0.f, 0.f, 0.f, 0.f};
    f32x4 acc[4][4];
#pragma unroll
    for (int m = 0; m < 4; m++)
#pragma unroll
        for (int n = 0; n < 4; n++) acc[m][n] = zero4;

    const int fr = lane & 15, kg = lane >> 4;
    const int s4 = kg ^ ((fr >> 2) & 3);
    const unsigned short* la = &lds_a[(wr * 64 + fr) * 32 + s4 * 8];
    const unsigned short* lb = &lds_b[(wc * 64 + fr) * 32 + s4 * 8];

    auto STAGE = [&](int buf, int k0) {
        const int o = buf << 12;
        gl16(pa0 + k0, &lds_a[o + wid * 512]);
        gl16(pa1 + k0, &lds_a[o + 2048 + wid * 512]);
        gl16(pb0 + k0, &lds_b[o + wid * 512]);
        gl16(pb1 + k0, &lds_b[o + 2048 + wid * 512]);
    };
    auto COMPUTE = [&](int buf) {
        const int o = buf << 12;
        bf16x8 af[4], bfr[4];
#pragma unroll
        for (int m = 0; m < 4; m++) af[m] = *(const bf16x8*)(la + o + m * 16 * 32);
#pragma unroll
        for (int n = 0; n < 4; n++) bfr[n] = *(const bf16x8*)(lb + o + n * 16 * 32);
#pragma unroll
        for (int m = 0; m < 4; m++)
#pragma unroll
            for (int n = 0; n < 4; n++) acc[m][n] = mfma16(af[m], bfr[n], acc[m][n]);
    };

    const int nsteps = K >> 5;
    STAGE(0, 0);
    STAGE(1, 32);

    int bc = 0, bs = 2;
    for (int s = 0; s < nsteps - 1; ++s) {
        asm volatile("s_waitcnt vmcnt(4)" ::: "memory");
        __builtin_amdgcn_s_barrier();
        const int k2 = (s + 2) << 5;
        if (k2 < K) STAGE(bs, k2);
        __builtin_amdgcn_sched_barrier(0);
        COMPUTE(bc);
        bc = (bc == 2) ? 0 : bc + 1;
        bs = (bs == 2) ? 0 : bs + 1;
    }
    asm volatile("s_waitcnt vmcnt(0)" ::: "memory");
    __builtin_amdgcn_s_barrier();
    COMPUTE(bc);

#pragma unroll
    for (int n = 0; n < 4; n++) {
        int col = col0 + wc * 64 + n * 16 + fr;
        float bv = bias[col];
#pragma unroll
        for (int m = 0; m < 4; m++) {
            long rb = row0 + wr * 64 + m * 16 + kg * 4;
#pragma unroll
            for (int r = 0; r < 4; r++) {
                long rr = rb + r;
                if (rr < M) {
                    float v = acc[m][n][r] + bv;
                    if (RELU) v = fmaxf(v, 0.f);
                    long idx = rr * Nc + col;
                    if (WB) outb[idx] = f2bf(v);
                    if (WF) outf[idx] = v;
                }
            }
        }
    }
}

// ---------------- big-GEMM: 256xBN tile, BK=64, 8 waves, m230-V0 2-phase schedule -------
// Guide T3 "minimum 2-phase" (682 TF refcheck'd @4096^3): stage-first into buf^1, compute
// buf barrier-free, ONE vmcnt(0)+s_barrier per K-tile. Fixes vs r4's failed 256^2:
//  (1) coalescing-preserving 8-slot XOR swizzle (slot' = slot ^ (row&7); rows = 128B/8 slots
//      -> read banks 2-way free, write side still covers full contiguous 128B per 8 lanes);
//  (2) LDS-staged coalesced epilogue (16B/lane stores; r4's scalar-short stores caused a
//      2.4x write storm).
template <int RELU, int BN>
__global__ __launch_bounds__(512, 2)
void k_gemm_big(const unsigned short* __restrict__ A, const unsigned short* __restrict__ WT,
                const float* __restrict__ bias, int M, int K, int Nc,
                unsigned short* __restrict__ outb) {
    constexpr int BM = 256;
    constexpr int NB = BN / 64;                 // B staging issues per wave (4 or 2)
    constexpr int WN = (BN == 256) ? 4 : 2;     // wave grid: 2Mx4N or 4Mx2N
    constexpr int MR = (BN == 256) ? 8 : 4;     // A-frags per wave (wave rows = MR*16)
    __shared__ __align__(16) unsigned short lds_a[2 * 16384];      // 2 x [256][64]
    __shared__ __align__(16) unsigned short lds_b[2 * BN * 64];    // 2 x [BN][64]

    const int tid = threadIdx.x, wid = tid >> 6, lane = tid & 63;
    const int fr = lane & 15, kg = lane >> 4;
    const int l8 = lane >> 3, l7 = lane & 7;
    const int slot_src = l7 ^ l8;               // write-side inverse of read swizzle

    // bijective XCD swizzle
    const int nwg = gridDim.x;
    const int q = nwg >> 3, r8v = nwg & 7;
    const int xcd = blockIdx.x & 7, sl = blockIdx.x >> 3;
    const int bid = (xcd < r8v ? xcd * (q + 1) : r8v * (q + 1) + (xcd - r8v) * q) + sl;

    const int ntN = Nc / BN;
    const int tM = bid / ntN, tN = bid - tM * ntN;
    const long row0 = (long)tM * 256;
    const int col0 = tN * BN;
    const int wr = wid / WN, wn = wid % WN;

    // staging sources: issue j covers rows [j*64 + wid*8, +8), lane: row += l8, slot l7
    const unsigned short* pa[4];
    const unsigned short* pb[4];
#pragma unroll
    for (int j = 0; j < 4; ++j) {
        long rr = row0 + j * 64 + wid * 8 + l8;
        if (rr > (long)M - 1) rr = M - 1;
        pa[j] = A + rr * K + slot_src * 8;
    }
#pragma unroll
    for (int j = 0; j < NB; ++j) {
        long rc = (long)col0 + j * 64 + wid * 8 + l8;
        pb[j] = WT + rc * K + slot_src * 8;
    }

    f32x4 zero4 = {0.f, 0.f, 0.f, 0.f};
    f32x4 acc[MR][4];
#pragma unroll
    for (int m = 0; m < MR; m++)
#pragma unroll
        for (int n = 0; n < 4; n++) acc[m][n] = zero4;

    auto STAGE = [&](int buf, int k0) {
#pragma unroll
        for (int j = 0; j < 4; ++j)
            gl16(pa[j] + k0, &lds_a[buf * 16384 + j * 4096 + wid * 512]);
#pragma unroll
        for (int j = 0; j < NB; ++j)
            gl16(pb[j] + k0, &lds_b[buf * (BN * 64) + j * 4096 + wid * 512]);
    };
    auto COMPUTE = [&](int buf) {
#pragma unroll
        for (int kh = 0; kh < 2; ++kh) {
            const int sw = ((kh * 4 + kg) ^ (fr & 7)) * 8;   // swizzled 16B slot in row
            bf16x8 af[MR], bfr[4];
#pragma unroll
            for (int m = 0; m < MR; m++)
                af[m] = *(const bf16x8*)&lds_a[buf * 16384 + (wr * (MR * 16) + m * 16 + fr) * 64 + sw];
#pragma unroll
            for (int n = 0; n < 4; n++)
                bfr[n] = *(const bf16x8*)&lds_b[buf * (BN * 64) + (wn * 64 + n * 16 + fr) * 64 + sw];
#pragma unroll
            for (int m = 0; m < MR; m++)
#pragma unroll
                for (int n = 0; n < 4; n++) acc[m][n] = mfma16(af[m], bfr[n], acc[m][n]);
        }
    };

    const int nkt = K >> 6;
    STAGE(0, 0);
    asm volatile("s_waitcnt vmcnt(0)" ::: "memory");
    __builtin_amdgcn_s_barrier();

    int buf = 0;
    for (int kt = 0; kt < nkt; ++kt) {
        if (kt + 1 < nkt) STAGE(buf ^ 1, (kt + 1) << 6);
        COMPUTE(buf);
        if (kt + 1 < nkt) {
            asm volatile("s_waitcnt vmcnt(0)" ::: "memory");
            __builtin_amdgcn_s_barrier();
        }
        buf ^= 1;
    }
    __syncthreads();   // LDS reuse for epilogue

    // ---- coalesced epilogue: 4 passes of 64 rows via lds_a (bias+RELU applied on write) ----
    float bv[4];
#pragma unroll
    for (int n = 0; n < 4; n++) bv[n] = bias[col0 + wn * 64 + n * 16 + fr];
    unsigned short* eld = lds_a;
    constexpr int ROUNDS = (64 * BN) / 4096;   // 16B store rounds per pass (4 or 2)
#pragma unroll
    for (int p = 0; p < 4; ++p) {
        const bool part = (BN == 256) ? (wr == (p >> 1)) : (wr == p);
        if (part) {
            const int mb = (BN == 256) ? ((p & 1) * 4) : 0;
#pragma unroll
            for (int mm = 0; mm < 4; ++mm) {
                const int m = mb + mm;
                const int rl = mm * 16 + kg * 4;   // row within the 64-row pass
#pragma unroll
                for (int n = 0; n < 4; ++n) {
                    const int cl = wn * 64 + n * 16 + fr;
#pragma unroll
                    for (int r = 0; r < 4; ++r) {
                        float v = acc[m][n][r] + bv[n];
                        if (RELU) v = fmaxf(v, 0.f);
                        eld[(rl + r) * BN + cl] = f2bf(v);
                    }
                }
            }
        }
        __syncthreads();
#pragma unroll
        for (int jj = 0; jj < ROUNDS; ++jj) {
            const int e = jj * 4096 + tid * 8;
            const int row = e / BN, col = e % BN;
            const long gr = row0 + p * 64 + row;
            if (gr < M) {
                uint4 v = *(const uint4*)&eld[e];
                *(uint4*)&outb[gr * Nc + col0 + col] = v;
            }
        }
        __syncthreads();
    }
}

// ---------------- fused layer-B GEMM + LayerNorm(256) + ReLU + residual ----------------
__global__ __launch_bounds__(512)
void k_gemm_fused_ln(const unsigned short* __restrict__ A, const unsigned short* __restrict__ WT,
                     const float* __restrict__ bias, const float* __restrict__ g,
                     const float* __restrict__ b, float* __restrict__ hf,
                     unsigned short* __restrict__ hb, int M) {
    __shared__ __align__(16) unsigned short lds_a[3 * 4096];   // 3 x [128][32]
    __shared__ __align__(16) unsigned short lds_b[3 * 8192];   // 3 x [256][32]
    __shared__ float red_s[128][4];
    __shared__ float red_q[128][4];
    const int tid = threadIdx.x, wid = tid >> 6, lane = tid & 63;
    const int fr = lane & 15, kg = lane >> 4;

    const int nwg = gridDim.x;
    const int q = nwg >> 3, r8 = nwg & 7;
    const int xcd = blockIdx.x & 7, sl = blockIdx.x >> 3;
    const int bid = (xcd < r8 ? xcd * (q + 1) : r8 * (q + 1) + (xcd - r8) * q) + sl;
    const long row0 = (long)bid * 128;
    const int wr = wid >> 2, wn = wid & 3;

    const int srow = lane >> 2, slot = lane & 3;
    long ar = row0 + wid * 16 + srow; if (ar > (long)M - 1) ar = M - 1;
    const unsigned short* pa  = A + ar * 256 + slot * 8;
    const unsigned short* pb0 = WT + (long)(wid * 16 + srow) * 256 + slot * 8;
    const unsigned short* pb1 = WT + (long)(128 + wid * 16 + srow) * 256 + slot * 8;

    f32x4 zero4 = {0.f, 0.f, 0.f, 0.f};
    f32x4 acc[4][4];
#pragma unroll
    for (int m = 0; m < 4; m++)
#pragma unroll
        for (int n = 0; n < 4; n++) acc[m][n] = zero4;

    auto STAGE = [&](int buf, int k0) {
        gl16(pa + k0, &lds_a[buf * 4096 + wid * 512]);
        gl16(pb0 + k0, &lds_b[buf * 8192 + wid * 512]);
        gl16(pb1 + k0, &lds_b[buf * 8192 + 4096 + wid * 512]);
    };
    auto COMPUTE = [&](int buf) {
        bf16x8 af[4], bfr[4];
#pragma unroll
        for (int m = 0; m < 4; m++)
            af[m] = *(const bf16x8*)&lds_a[buf * 4096 + (wr * 64 + m * 16 + fr) * 32 + kg * 8];
#pragma unroll
        for (int n = 0; n < 4; n++)
            bfr[n] = *(const bf16x8*)&lds_b[buf * 8192 + (wn * 64 + n * 16 + fr) * 32 + kg * 8];
#pragma unroll
        for (int m = 0; m < 4; m++)
#pragma unroll
            for (int n = 0; n < 4; n++) acc[m][n] = mfma16(af[m], bfr[n], acc[m][n]);
    };

    STAGE(0, 0);
    STAGE(1, 32);
    int bc = 0, bs = 2;
    for (int s = 0; s < 7; ++s) {
        asm volatile("s_waitcnt vmcnt(3)" ::: "memory");
        __builtin_amdgcn_s_barrier();
        const int k2 = (s + 2) << 5;
        if (k2 < 256) STAGE(bs, k2);
        __builtin_amdgcn_sched_barrier(0);
        COMPUTE(bc);
        bc = (bc == 2) ? 0 : bc + 1;
        bs = (bs == 2) ? 0 : bs + 1;
    }
    asm volatile("s_waitcnt vmcnt(0)" ::: "memory");
    __builtin_amdgcn_s_barrier();
    COMPUTE(bc);

    float bv[4], gv[4], betav[4];
#pragma unroll
    for (int n = 0; n < 4; n++) {
        int col = wn * 64 + n * 16 + fr;
        bv[n] = bias[col];
        gv[n] = g[col];
        betav[n] = b[col];
    }
#pragma unroll
    for (int m = 0; m < 4; m++) {
#pragma unroll
        for (int r = 0; r < 4; r++) {
            float s = 0.f, q2 = 0.f;
#pragma unroll
            for (int n = 0; n < 4; n++) {
                float z = acc[m][n][r] + bv[n];
                s += z;
                q2 += z * z;
            }
#pragma unroll
            for (int off = 1; off < 16; off <<= 1) {
                s += __shfl_xor(s, off);
                q2 += __shfl_xor(q2, off);
            }
            if (fr == 0) {
                int rl = wr * 64 + m * 16 + kg * 4 + r;
                red_s[rl][wn] = s;
                red_q[rl][wn] = q2;
            }
        }
    }
    __syncthreads();
#pragma unroll
    for (int m = 0; m < 4; m++) {
#pragma unroll
        for (int r = 0; r < 4; r++) {
            const int rl = wr * 64 + m * 16 + kg * 4 + r;
            const long rr = row0 + rl;
            float S = red_s[rl][0] + red_s[rl][1] + red_s[rl][2] + red_s[rl][3];
            float Q = red_q[rl][0] + red_q[rl][1] + red_q[rl][2] + red_q[rl][3];
            float mean = S * (1.f / 256.f);
            float var = Q * (1.f / 256.f) - mean * mean;
            float inv = rsqrtf(var + 1e-5f);
            if (rr < M) {
#pragma unroll
                for (int n = 0; n < 4; n++) {
                    int col = wn * 64 + n * 16 + fr;
                    float z = acc[m][n][r] + bv[n];
                    long idx = rr * 256 + col;
                    float o = hf[idx] + fmaxf((z - mean) * inv * gv[n] + betav[n], 0.f);
                    hf[idx] = o;
                    hb[idx] = f2bf(o);
                }
            }
        }
    }
}

// ---------------- host orchestration ----------------
extern "C" void kernel_launch(void* const* d_in, const int* in_sizes, int n_in,
                              void* d_out, int out_size, void* d_ws, size_t ws_size,
                              hipStream_t stream) {
    const float* x    = (const float*)d_in[0];
    const int*   eidx = (const int*)d_in[1];
    const float* ln_g = (const float*)d_in[2];
    const float* ln_b = (const float*)d_in[3];
    const float* W1   = (const float*)d_in[4];
    const float* b1   = (const float*)d_in[5];
    const float* W2   = (const float*)d_in[6];
    const float* b2   = (const float*)d_in[7];
    const float* Wa   = (const float*)d_in[8];
    const float* ba   = (const float*)d_in[9];
    const float* Wb   = (const float*)d_in[10];
    const float* bb   = (const float*)d_in[11];
    const float* ng   = (const float*)d_in[12];
    const float* nbt  = (const float*)d_in[13];
    const float* Wd1  = (const float*)d_in[14];
    const float* bd1  = (const float*)d_in[15];
    const float* Wd2  = (const float*)d_in[16];
    const float* bd2  = (const float*)d_in[17];
    const float* outg = (const float*)d_in[18];
    const float* outbeta = (const float*)d_in[19];
    float* out = (float*)d_out;

    const int N = in_sizes[0] / 1024;  // 50000
    const int E = in_sizes[1] / 2;     // 800000
    const int* e_src = eidx;
    const int* e_dst = eidx + E;

    char* ws = (char*)d_ws;
    size_t off = 0;
    auto alloc = [&](size_t bytes) -> char* {
        char* p = ws + off;
        off += (bytes + 255) & ~(size_t)255;
        return p;
    };

    unsigned short* xln = (unsigned short*)alloc((size_t)N * 1024 * 2);
    unsigned short* zb16 = xln;                                          // N*256 bf16
    unsigned short* za   = (unsigned short*)((char*)xln + (size_t)N * 256 * 2);  // N*256 bf16
    unsigned short* delta = xln;                                         // N*1024 bf16

    unsigned short* h1 = (unsigned short*)alloc((size_t)N * 512 * 2);    // also d1
    float*          hf = (float*)alloc((size_t)N * 256 * 4);
    unsigned short* hb = (unsigned short*)alloc((size_t)N * 256 * 2);

    unsigned short* W1T  = (unsigned short*)alloc((size_t)512 * 1024 * 2);
    unsigned short* W2T  = (unsigned short*)alloc((size_t)256 * 512 * 2);
    unsigned short* WaT  = (unsigned short*)alloc((size_t)3 * 256 * 256 * 2);
    unsigned short* WbT  = (unsigned short*)alloc((size_t)3 * 256 * 256 * 2);
    unsigned short* Wd1T = (unsigned short*)alloc((size_t)512 * 256 * 2);
    unsigned short* Wd2T = (unsigned short*)alloc((size_t)1024 * 512 * 2);

    int* deg  = (int*)alloc((size_t)(N + 1) * 4);
    int* rp   = (int*)alloc((size_t)(N + 1) * 4);
    int* cur  = (int*)alloc((size_t)N * 4);
    int* bsum = (int*)alloc(64 * 4);
    int* boff = (int*)alloc(64 * 4);
    int* esrc = (int*)alloc((size_t)E * 4);

    auto cdiv = [](long a, long b) { return (int)((a + b - 1) / b); };

    k_transpose_all<<<6656, 256, 0, stream>>>(W1, W2, Wa, Wb, Wd1, Wd2,
                                              W1T, W2T, WaT, WbT, Wd1T, Wd2T);

    k_zero_i32<<<cdiv(N, 256), 256, 0, stream>>>(deg, N);
    k_hist<<<cdiv(E, 256), 256, 0, stream>>>(e_dst, E, deg);
    int nb1 = cdiv(N, 1024);  // 49
    k_scan1<<<nb1, 1024, 0, stream>>>(deg, rp, bsum, N);
    k_scan2<<<1, 64, 0, stream>>>(bsum, boff, nb1);
    k_scan3<<<cdiv(N, 256), 256, 0, stream>>>(rp, boff, cur, N, E);
    k_fill<<<cdiv(E, 256), 256, 0, stream>>>(e_src, e_dst, E, cur, esrc);

    const int ntM = cdiv(N, 128);   // 391
    const int ntM2 = cdiv(N, 256);  // 196

    // in_proj: big-GEMM for W1 (256x128 tile, 784 blocks)
    k_ln1024_in<<<N, 256, 0, stream>>>(x, ln_g, ln_b, xln);
    k_gemm_big<1, 128><<<ntM2 * 4, 512, 0, stream>>>(xln, W1T, b1, N, 1024, 512, h1);
    k_gemm<0, 1, 1><<<ntM * 2, 256, 0, stream>>>(h1, W2T, b2, N, 512, 256, hb, hf);

    // GNN blocks
    for (int i = 0; i < 3; i++) {
        k_agg<<<cdiv(N, 4), 256, 0, stream>>>(hf, hb, rp, esrc, zb16, N);
        k_gemm<1, 1, 0><<<ntM * 2, 256, 0, stream>>>(zb16, WaT + (size_t)i * 65536, ba + (size_t)i * 256,
                                                     N, 256, 256, za, nullptr);
        k_gemm_fused_ln<<<ntM, 512, 0, stream>>>(za, WbT + (size_t)i * 65536, bb + (size_t)i * 256,
                                                 ng + (size_t)i * 256, nbt + (size_t)i * 256,
                                                 hf, hb, N);
    }

    // delta_proj + output LN: big-GEMM for Wd2 (256x256 tile, 784 blocks)
    k_gemm<1, 1, 0><<<ntM * 4, 256, 0, stream>>>(hb, Wd1T, bd1, N, 256, 512, h1, nullptr);
    k_gemm_big<0, 256><<<ntM2 * 4, 512, 0, stream>>>(h1, Wd2T, bd2, N, 512, 1024, delta);
    k_ln1024_out<<<N, 256, 0, stream>>>(x, delta, outg, outbeta, out);
}

// Round 10
// 975.669 us; speedup vs baseline: 1.0130x; 1.0130x over previous
//
#include <hip/hip_runtime.h>
#include <hip/hip_bf16.h>

#define DEVI __device__ __forceinline__

using bf16x8 = __attribute__((ext_vector_type(8))) short;   // 8 bf16 in 4 VGPRs (per guide §3)
using f32x4  = __attribute__((ext_vector_type(4))) float;

DEVI unsigned short f2bf(float f) {
    unsigned u = __builtin_bit_cast(unsigned, f);
    return (unsigned short)((u + 0x7FFFu + ((u >> 16) & 1u)) >> 16);
}
DEVI float bf2f(unsigned short h) {
    return __builtin_bit_cast(float, (unsigned)h << 16);
}

DEVI f32x4 mfma16(bf16x8 a, bf16x8 b, f32x4 c) {
    return __builtin_amdgcn_mfma_f32_16x16x32_bf16(a, b, c, 0, 0, 0);
}

// async global->LDS, 16B per lane, LDS dest = wave-uniform base + lane*16 (guide §5)
DEVI void gl16(const void* g, void* l) {
    __builtin_amdgcn_global_load_lds((const __attribute__((address_space(1))) void*)g,
                                     (__attribute__((address_space(3))) void*)l,
                                     16, 0, 0);
}

// ---------------- ALL weight transposes + bf16 cast in ONE launch ----------------
__global__ void k_transpose_all(const float* __restrict__ W1, const float* __restrict__ W2,
                                const float* __restrict__ Wa, const float* __restrict__ Wb,
                                const float* __restrict__ Wd1, const float* __restrict__ Wd2,
                                unsigned short* __restrict__ W1T, unsigned short* __restrict__ W2T,
                                unsigned short* __restrict__ WaT, unsigned short* __restrict__ WbT,
                                unsigned short* __restrict__ Wd1T, unsigned short* __restrict__ Wd2T) {
    long i = (long)blockIdx.x * 256 + threadIdx.x;
    if (i < 524288) {                      // W1T: [512][1024] <- W1 [1024][512]
        int nn = (int)(i >> 10), kk = (int)(i & 1023);
        W1T[i] = f2bf(W1[(long)kk * 512 + nn]);
        return;
    }
    i -= 524288;
    if (i < 131072) {                      // W2T: [256][512] <- W2 [512][256]
        int nn = (int)(i >> 9), kk = (int)(i & 511);
        W2T[i] = f2bf(W2[(long)kk * 256 + nn]);
        return;
    }
    i -= 131072;
    if (i < 196608) {                      // WaT: 3 x [256][256]
        int li = (int)(i & 65535), layer = (int)(i >> 16);
        int nn = li >> 8, kk = li & 255;
        WaT[i] = f2bf(Wa[(long)layer * 65536 + (long)kk * 256 + nn]);
        return;
    }
    i -= 196608;
    if (i < 196608) {                      // WbT: 3 x [256][256]
        int li = (int)(i & 65535), layer = (int)(i >> 16);
        int nn = li >> 8, kk = li & 255;
        WbT[i] = f2bf(Wb[(long)layer * 65536 + (long)kk * 256 + nn]);
        return;
    }
    i -= 196608;
    if (i < 131072) {                      // Wd1T: [512][256] <- Wd1 [256][512]
        int nn = (int)(i >> 8), kk = (int)(i & 255);
        Wd1T[i] = f2bf(Wd1[(long)kk * 512 + nn]);
        return;
    }
    i -= 131072;
    if (i < 524288) {                      // Wd2T: [1024][512] <- Wd2 [512][1024]
        int nn = (int)(i >> 9), kk = (int)(i & 511);
        Wd2T[i] = f2bf(Wd2[(long)kk * 1024 + nn]);
    }
}

// ---------------- CSR build ----------------
__global__ void k_zero_i32(int* p, int n) {
    int i = blockIdx.x * 256 + threadIdx.x;
    if (i < n) p[i] = 0;
}
__global__ void k_hist(const int* __restrict__ dst, int E, int* __restrict__ deg) {
    int i = blockIdx.x * 256 + threadIdx.x;
    if (i < E) atomicAdd(&deg[dst[i]], 1);
}
__global__ __launch_bounds__(1024)
void k_scan1(const int* __restrict__ deg, int* __restrict__ rp, int* __restrict__ bsum, int n) {
    __shared__ int sh[1024];
    int t = threadIdx.x;
    int i = blockIdx.x * 1024 + t;
    int v = (i < n) ? deg[i] : 0;
    sh[t] = v;
    __syncthreads();
    for (int off = 1; off < 1024; off <<= 1) {
        int y = (t >= off) ? sh[t - off] : 0;
        __syncthreads();
        sh[t] += y;
        __syncthreads();
    }
    if (i < n) rp[i] = sh[t] - v;            // exclusive within block
    if (t == 1023) bsum[blockIdx.x] = sh[1023];
}
__global__ __launch_bounds__(64)
void k_scan2(const int* __restrict__ bsum, int* __restrict__ boff, int nb) {  // nb <= 64
    int lane = threadIdx.x;
    int v = (lane < nb) ? bsum[lane] : 0;
    int x = v;
    for (int off = 1; off < 64; off <<= 1) {
        int y = __shfl_up(x, off);
        if (lane >= off) x += y;
    }
    if (lane < nb) boff[lane] = x - v;
}
__global__ void k_scan3(int* __restrict__ rp, const int* __restrict__ boff,
                        int* __restrict__ cur, int n, int E) {
    int i = blockIdx.x * 256 + threadIdx.x;
    if (i < n) {
        int v = rp[i] + boff[i >> 10];
        rp[i] = v;
        cur[i] = v;
    }
    if (i == 0) rp[n] = E;
}
__global__ void k_fill(const int* __restrict__ src, const int* __restrict__ dst, int E,
                       int* __restrict__ cur, int* __restrict__ esrc) {
    int i = blockIdx.x * 256 + threadIdx.x;
    if (i < E) {
        int d = dst[i];
        int p = atomicAdd(&cur[d], 1);
        esrc[p] = src[i];
    }
}

// ---------------- LayerNorm kernels ----------------
__global__ __launch_bounds__(256)
void k_ln1024_in(const float* __restrict__ x, const float* __restrict__ g,
                 const float* __restrict__ b, unsigned short* __restrict__ out) {
    const long row = blockIdx.x;
    const int tid = threadIdx.x, lane = tid & 63, wid = tid >> 6;
    float4 v = ((const float4*)(x + row * 1024))[tid];
    float s = v.x + v.y + v.z + v.w;
    float s2 = v.x * v.x + v.y * v.y + v.z * v.z + v.w * v.w;
    for (int off = 1; off < 64; off <<= 1) { s += __shfl_xor(s, off); s2 += __shfl_xor(s2, off); }
    __shared__ float red[8];
    if (lane == 0) { red[wid] = s; red[4 + wid] = s2; }
    __syncthreads();
    s = red[0] + red[1] + red[2] + red[3];
    s2 = red[4] + red[5] + red[6] + red[7];
    float m = s * (1.f / 1024.f);
    float var = s2 * (1.f / 1024.f) - m * m;
    float inv = rsqrtf(var + 1e-5f);
    float4 gv = ((const float4*)g)[tid];
    float4 bv = ((const float4*)b)[tid];
    ushort4 o = make_ushort4(f2bf((v.x - m) * inv * gv.x + bv.x),
                             f2bf((v.y - m) * inv * gv.y + bv.y),
                             f2bf((v.z - m) * inv * gv.z + bv.z),
                             f2bf((v.w - m) * inv * gv.w + bv.w));
    ((ushort4*)(out + row * 1024))[tid] = o;
}

__global__ __launch_bounds__(256)
void k_ln1024_out(const float* __restrict__ x, const unsigned short* __restrict__ delta,
                  const float* __restrict__ g, const float* __restrict__ b,
                  float* __restrict__ out) {
    const long row = blockIdx.x;
    const int tid = threadIdx.x, lane = tid & 63, wid = tid >> 6;
    float4 xv = ((const float4*)(x + row * 1024))[tid];
    ushort4 dv = ((const ushort4*)(delta + row * 1024))[tid];
    float4 v;
    v.x = xv.x + bf2f(dv.x);
    v.y = xv.y + bf2f(dv.y);
    v.z = xv.z + bf2f(dv.z);
    v.w = xv.w + bf2f(dv.w);
    float s = v.x + v.y + v.z + v.w;
    float s2 = v.x * v.x + v.y * v.y + v.z * v.z + v.w * v.w;
    for (int off = 1; off < 64; off <<= 1) { s += __shfl_xor(s, off); s2 += __shfl_xor(s2, off); }
    __shared__ float red[8];
    if (lane == 0) { red[wid] = s; red[4 + wid] = s2; }
    __syncthreads();
    s = red[0] + red[1] + red[2] + red[3];
    s2 = red[4] + red[5] + red[6] + red[7];
    float m = s * (1.f / 1024.f);
    float var = s2 * (1.f / 1024.f) - m * m;
    float inv = rsqrtf(var + 1e-5f);
    float4 gv = ((const float4*)g)[tid];
    float4 bv = ((const float4*)b)[tid];
    float4 o;
    o.x = (v.x - m) * inv * gv.x + bv.x;
    o.y = (v.y - m) * inv * gv.y + bv.y;
    o.z = (v.z - m) * inv * gv.z + bv.z;
    o.w = (v.w - m) * inv * gv.w + bv.w;
    ((float4*)(out + row * 1024))[tid] = o;
}

// ---------------- aggregation: z[dst] = h[dst] + sum_{src in-edges} h[src] ----------------
__global__ __launch_bounds__(256)
void k_agg(const float* __restrict__ hf, const unsigned short* __restrict__ hb,
           const int* __restrict__ rp, const int* __restrict__ esrc,
           unsigned short* __restrict__ z, int n) {
    int node = blockIdx.x * 4 + (threadIdx.x >> 6);
    if (node >= n) return;
    int lane = threadIdx.x & 63;
    float4 sv = ((const float4*)(hf + (long)node * 256))[lane];
    float a0 = sv.x, a1 = sv.y, a2 = sv.z, a3 = sv.w;
    int beg = rp[node], end = rp[node + 1];
    int e = beg;
    for (; e + 4 <= end; e += 4) {
        int s0 = esrc[e], s1 = esrc[e + 1], s2 = esrc[e + 2], s3 = esrc[e + 3];
        ushort4 v0 = ((const ushort4*)(hb + (long)s0 * 256))[lane];
        ushort4 v1 = ((const ushort4*)(hb + (long)s1 * 256))[lane];
        ushort4 v2 = ((const ushort4*)(hb + (long)s2 * 256))[lane];
        ushort4 v3 = ((const ushort4*)(hb + (long)s3 * 256))[lane];
        a0 += bf2f(v0.x) + bf2f(v1.x) + bf2f(v2.x) + bf2f(v3.x);
        a1 += bf2f(v0.y) + bf2f(v1.y) + bf2f(v2.y) + bf2f(v3.y);
        a2 += bf2f(v0.z) + bf2f(v1.z) + bf2f(v2.z) + bf2f(v3.z);
        a3 += bf2f(v0.w) + bf2f(v1.w) + bf2f(v2.w) + bf2f(v3.w);
    }
    for (; e < end; ++e) {
        int s = esrc[e];
        ushort4 hv = ((const ushort4*)(hb + (long)s * 256))[lane];
        a0 += bf2f(hv.x);
        a1 += bf2f(hv.y);
        a2 += bf2f(hv.z);
        a3 += bf2f(hv.w);
    }
    ushort4 o = make_ushort4(f2bf(a0), f2bf(a1), f2bf(a2), f2bf(a3));
    ((ushort4*)(z + (long)node * 256))[lane] = o;
}

// ---------------- bf16 MFMA GEMM: 128x128 tile (r3 schedule, proven) ----------------
template <int RELU, int WB, int WF>
__global__ __launch_bounds__(256)
void k_gemm(const unsigned short* __restrict__ A, const unsigned short* __restrict__ WT,
            const float* __restrict__ bias, int M, int K, int Nc,
            unsigned short* __restrict__ outb, float* __restrict__ outf) {
    __shared__ __align__(16) unsigned short lds_a[3 * 4096];
    __shared__ __align__(16) unsigned short lds_b[3 * 4096];
    const int tid = threadIdx.x;
    const int wid = tid >> 6, lane = tid & 63;

    const int nwg = gridDim.x;
    const int q = nwg >> 3, r8 = nwg & 7;
    const int xcd = blockIdx.x & 7, sl = blockIdx.x >> 3;
    const int bid = (xcd < r8 ? xcd * (q + 1) : r8 * (q + 1) + (xcd - r8) * q) + sl;

    const int ntN = Nc >> 7;
    const int tM = bid / ntN, tN = bid - tM * ntN;
    const long row0 = (long)tM * 128;
    const int col0 = tN << 7;
    const int wr = wid >> 1, wc = wid & 1;

    const int sr = tid >> 2;
    const int sc = (((tid & 3) ^ ((sr >> 2) & 3)) << 3);
    long ra0 = row0 + sr;       if (ra0 > (long)M - 1) ra0 = M - 1;
    long ra1 = row0 + sr + 64;  if (ra1 > (long)M - 1) ra1 = M - 1;
    const unsigned short* pa0 = A + ra0 * K + sc;
    const unsigned short* pa1 = A + ra1 * K + sc;
    const unsigned short* pb0 = WT + (long)(col0 + sr) * K + sc;
    const unsigned short* pb1 = WT + (long)(col0 + sr + 64) * K + sc;

    f32x4 zero4 = {0.f, 0.f, 0.f, 0.f};
    f32x4 acc[4][4];
#pragma unroll
    for (int m = 0; m < 4; m++)
#pragma unroll
        for (int n = 0; n < 4; n++) acc[m][n] = zero4;

    const int fr = lane & 15, kg = lane >> 4;
    const int s4 = kg ^ ((fr >> 2) & 3);
    const unsigned short* la = &lds_a[(wr * 64 + fr) * 32 + s4 * 8];
    const unsigned short* lb = &lds_b[(wc * 64 + fr) * 32 + s4 * 8];

    auto STAGE = [&](int buf, int k0) {
        const int o = buf << 12;
        gl16(pa0 + k0, &lds_a[o + wid * 512]);
        gl16(pa1 + k0, &lds_a[o + 2048 + wid * 512]);
        gl16(pb0 + k0, &lds_b[o + wid * 512]);
        gl16(pb1 + k0, &lds_b[o + 2048 + wid * 512]);
    };
    auto COMPUTE = [&](int buf) {
        const int o = buf << 12;
        bf16x8 af[4], bfr[4];
#pragma unroll
        for (int m = 0; m < 4; m++) af[m] = *(const bf16x8*)(la + o + m * 16 * 32);
#pragma unroll
        for (int n = 0; n < 4; n++) bfr[n] = *(const bf16x8*)(lb + o + n * 16 * 32);
#pragma unroll
        for (int m = 0; m < 4; m++)
#pragma unroll
            for (int n = 0; n < 4; n++) acc[m][n] = mfma16(af[m], bfr[n], acc[m][n]);
    };

    const int nsteps = K >> 5;
    STAGE(0, 0);
    STAGE(1, 32);

    int bc = 0, bs = 2;
    for (int s = 0; s < nsteps - 1; ++s) {
        asm volatile("s_waitcnt vmcnt(4)" ::: "memory");
        __builtin_amdgcn_s_barrier();
        const int k2 = (s + 2) << 5;
        if (k2 < K) STAGE(bs, k2);
        __builtin_amdgcn_sched_barrier(0);
        COMPUTE(bc);
        bc = (bc == 2) ? 0 : bc + 1;
        bs = (bs == 2) ? 0 : bs + 1;
    }
    asm volatile("s_waitcnt vmcnt(0)" ::: "memory");
    __builtin_amdgcn_s_barrier();
    COMPUTE(bc);

#pragma unroll
    for (int n = 0; n < 4; n++) {
        int col = col0 + wc * 64 + n * 16 + fr;
        float bv = bias[col];
#pragma unroll
        for (int m = 0; m < 4; m++) {
            long rb = row0 + wr * 64 + m * 16 + kg * 4;
#pragma unroll
            for (int r = 0; r < 4; r++) {
                long rr = rb + r;
                if (rr < M) {
                    float v = acc[m][n][r] + bv;
                    if (RELU) v = fmaxf(v, 0.f);
                    long idx = rr * Nc + col;
                    if (WB) outb[idx] = f2bf(v);
                    if (WF) outf[idx] = v;
                }
            }
        }
    }
}

// ---------------- big-GEMM: 256x256 tile, BK=64, 8 waves, m230-V0 2-phase schedule -------
// Measured r9: Wd2 (K=512, Nc=1024) ~124 us with this kernel vs 142 with k_gemm.
// KEPT for Wd2 only; the BN=128 variant regressed (153 vs ~135) -> W1 reverted to k_gemm.
// Mechanism: 64 MFMA/wave per drain-point amortizes the per-K-tile vmcnt(0); BN=128's 32
// MFMA + 15 drain points left latency exposed at 1 block/CU.
template <int RELU, int BN>
__global__ __launch_bounds__(512, 2)
void k_gemm_big(const unsigned short* __restrict__ A, const unsigned short* __restrict__ WT,
                const float* __restrict__ bias, int M, int K, int Nc,
                unsigned short* __restrict__ outb) {
    constexpr int NB = BN / 64;                 // B staging issues per wave
    constexpr int WN = (BN == 256) ? 4 : 2;
    constexpr int MR = (BN == 256) ? 8 : 4;
    __shared__ __align__(16) unsigned short lds_a[2 * 16384];      // 2 x [256][64]
    __shared__ __align__(16) unsigned short lds_b[2 * BN * 64];    // 2 x [BN][64]

    const int tid = threadIdx.x, wid = tid >> 6, lane = tid & 63;
    const int fr = lane & 15, kg = lane >> 4;
    const int l8 = lane >> 3, l7 = lane & 7;
    const int slot_src = l7 ^ l8;               // write-side inverse of read swizzle

    const int nwg = gridDim.x;
    const int q = nwg >> 3, r8v = nwg & 7;
    const int xcd = blockIdx.x & 7, sl = blockIdx.x >> 3;
    const int bid = (xcd < r8v ? xcd * (q + 1) : r8v * (q + 1) + (xcd - r8v) * q) + sl;

    const int ntN = Nc / BN;
    const int tM = bid / ntN, tN = bid - tM * ntN;
    const long row0 = (long)tM * 256;
    const int col0 = tN * BN;
    const int wr = wid / WN, wn = wid % WN;

    const unsigned short* pa[4];
    const unsigned short* pb[4];
#pragma unroll
    for (int j = 0; j < 4; ++j) {
        long rr = row0 + j * 64 + wid * 8 + l8;
        if (rr > (long)M - 1) rr = M - 1;
        pa[j] = A + rr * K + slot_src * 8;
    }
#pragma unroll
    for (int j = 0; j < NB; ++j) {
        long rc = (long)col0 + j * 64 + wid * 8 + l8;
        pb[j] = WT + rc * K + slot_src * 8;
    }

    f32x4 zero4 = {0.f, 0.f, 0.f, 0.f};
    f32x4 acc[MR][4];
#pragma unroll
    for (int m = 0; m < MR; m++)
#pragma unroll
        for (int n = 0; n < 4; n++) acc[m][n] = zero4;

    auto STAGE = [&](int buf, int k0) {
#pragma unroll
        for (int j = 0; j < 4; ++j)
            gl16(pa[j] + k0, &lds_a[buf * 16384 + j * 4096 + wid * 512]);
#pragma unroll
        for (int j = 0; j < NB; ++j)
            gl16(pb[j] + k0, &lds_b[buf * (BN * 64) + j * 4096 + wid * 512]);
    };
    auto COMPUTE = [&](int buf) {
#pragma unroll
        for (int kh = 0; kh < 2; ++kh) {
            const int sw = ((kh * 4 + kg) ^ (fr & 7)) * 8;   // swizzled 16B slot in row
            bf16x8 af[MR], bfr[4];
#pragma unroll
            for (int m = 0; m < MR; m++)
                af[m] = *(const bf16x8*)&lds_a[buf * 16384 + (wr * (MR * 16) + m * 16 + fr) * 64 + sw];
#pragma unroll
            for (int n = 0; n < 4; n++)
                bfr[n] = *(const bf16x8*)&lds_b[buf * (BN * 64) + (wn * 64 + n * 16 + fr) * 64 + sw];
#pragma unroll
            for (int m = 0; m < MR; m++)
#pragma unroll
                for (int n = 0; n < 4; n++) acc[m][n] = mfma16(af[m], bfr[n], acc[m][n]);
        }
    };

    const int nkt = K >> 6;
    STAGE(0, 0);
    asm volatile("s_waitcnt vmcnt(0)" ::: "memory");
    __builtin_amdgcn_s_barrier();

    int buf = 0;
    for (int kt = 0; kt < nkt; ++kt) {
        if (kt + 1 < nkt) STAGE(buf ^ 1, (kt + 1) << 6);
        COMPUTE(buf);
        if (kt + 1 < nkt) {
            asm volatile("s_waitcnt vmcnt(0)" ::: "memory");
            __builtin_amdgcn_s_barrier();
        }
        buf ^= 1;
    }
    __syncthreads();   // LDS reuse for epilogue

    // ---- coalesced epilogue: 4 passes of 64 rows via lds_a ----
    float bv[4];
#pragma unroll
    for (int n = 0; n < 4; n++) bv[n] = bias[col0 + wn * 64 + n * 16 + fr];
    unsigned short* eld = lds_a;
    constexpr int ROUNDS = (64 * BN) / 4096;
#pragma unroll
    for (int p = 0; p < 4; ++p) {
        const bool part = (BN == 256) ? (wr == (p >> 1)) : (wr == p);
        if (part) {
            const int mb = (BN == 256) ? ((p & 1) * 4) : 0;
#pragma unroll
            for (int mm = 0; mm < 4; ++mm) {
                const int m = mb + mm;
                const int rl = mm * 16 + kg * 4;
#pragma unroll
                for (int n = 0; n < 4; ++n) {
                    const int cl = wn * 64 + n * 16 + fr;
#pragma unroll
                    for (int r = 0; r < 4; ++r) {
                        float v = acc[m][n][r] + bv[n];
                        if (RELU) v = fmaxf(v, 0.f);
                        eld[(rl + r) * BN + cl] = f2bf(v);
                    }
                }
            }
        }
        __syncthreads();
#pragma unroll
        for (int jj = 0; jj < ROUNDS; ++jj) {
            const int e = jj * 4096 + tid * 8;
            const int row = e / BN, col = e % BN;
            const long gr = row0 + p * 64 + row;
            if (gr < M) {
                uint4 v = *(const uint4*)&eld[e];
                *(uint4*)&outb[gr * Nc + col0 + col] = v;
            }
        }
        __syncthreads();
    }
}

// ---------------- fused layer-B GEMM + LayerNorm(256) + ReLU + residual ----------------
__global__ __launch_bounds__(512)
void k_gemm_fused_ln(const unsigned short* __restrict__ A, const unsigned short* __restrict__ WT,
                     const float* __restrict__ bias, const float* __restrict__ g,
                     const float* __restrict__ b, float* __restrict__ hf,
                     unsigned short* __restrict__ hb, int M) {
    __shared__ __align__(16) unsigned short lds_a[3 * 4096];   // 3 x [128][32]
    __shared__ __align__(16) unsigned short lds_b[3 * 8192];   // 3 x [256][32]
    __shared__ float red_s[128][4];
    __shared__ float red_q[128][4];
    const int tid = threadIdx.x, wid = tid >> 6, lane = tid & 63;
    const int fr = lane & 15, kg = lane >> 4;

    const int nwg = gridDim.x;
    const int q = nwg >> 3, r8 = nwg & 7;
    const int xcd = blockIdx.x & 7, sl = blockIdx.x >> 3;
    const int bid = (xcd < r8 ? xcd * (q + 1) : r8 * (q + 1) + (xcd - r8) * q) + sl;
    const long row0 = (long)bid * 128;
    const int wr = wid >> 2, wn = wid & 3;

    const int srow = lane >> 2, slot = lane & 3;
    long ar = row0 + wid * 16 + srow; if (ar > (long)M - 1) ar = M - 1;
    const unsigned short* pa  = A + ar * 256 + slot * 8;
    const unsigned short* pb0 = WT + (long)(wid * 16 + srow) * 256 + slot * 8;
    const unsigned short* pb1 = WT + (long)(128 + wid * 16 + srow) * 256 + slot * 8;

    f32x4 zero4 = {0.f, 0.f, 0.f, 0.f};
    f32x4 acc[4][4];
#pragma unroll
    for (int m = 0; m < 4; m++)
#pragma unroll
        for (int n = 0; n < 4; n++) acc[m][n] = zero4;

    auto STAGE = [&](int buf, int k0) {
        gl16(pa + k0, &lds_a[buf * 4096 + wid * 512]);
        gl16(pb0 + k0, &lds_b[buf * 8192 + wid * 512]);
        gl16(pb1 + k0, &lds_b[buf * 8192 + 4096 + wid * 512]);
    };
    auto COMPUTE = [&](int buf) {
        bf16x8 af[4], bfr[4];
#pragma unroll
        for (int m = 0; m < 4; m++)
            af[m] = *(const bf16x8*)&lds_a[buf * 4096 + (wr * 64 + m * 16 + fr) * 32 + kg * 8];
#pragma unroll
        for (int n = 0; n < 4; n++)
            bfr[n] = *(const bf16x8*)&lds_b[buf * 8192 + (wn * 64 + n * 16 + fr) * 32 + kg * 8];
#pragma unroll
        for (int m = 0; m < 4; m++)
#pragma unroll
            for (int n = 0; n < 4; n++) acc[m][n] = mfma16(af[m], bfr[n], acc[m][n]);
    };

    STAGE(0, 0);
    STAGE(1, 32);
    int bc = 0, bs = 2;
    for (int s = 0; s < 7; ++s) {
        asm volatile("s_waitcnt vmcnt(3)" ::: "memory");
        __builtin_amdgcn_s_barrier();
        const int k2 = (s + 2) << 5;
        if (k2 < 256) STAGE(bs, k2);
        __builtin_amdgcn_sched_barrier(0);
        COMPUTE(bc);
        bc = (bc == 2) ? 0 : bc + 1;
        bs = (bs == 2) ? 0 : bs + 1;
    }
    asm volatile("s_waitcnt vmcnt(0)" ::: "memory");
    __builtin_amdgcn_s_barrier();
    COMPUTE(bc);

    float bv[4], gv[4], betav[4];
#pragma unroll
    for (int n = 0; n < 4; n++) {
        int col = wn * 64 + n * 16 + fr;
        bv[n] = bias[col];
        gv[n] = g[col];
        betav[n] = b[col];
    }
#pragma unroll
    for (int m = 0; m < 4; m++) {
#pragma unroll
        for (int r = 0; r < 4; r++) {
            float s = 0.f, q2 = 0.f;
#pragma unroll
            for (int n = 0; n < 4; n++) {
                float z = acc[m][n][r] + bv[n];
                s += z;
                q2 += z * z;
            }
#pragma unroll
            for (int off = 1; off < 16; off <<= 1) {
                s += __shfl_xor(s, off);
                q2 += __shfl_xor(q2, off);
            }
            if (fr == 0) {
                int rl = wr * 64 + m * 16 + kg * 4 + r;
                red_s[rl][wn] = s;
                red_q[rl][wn] = q2;
            }
        }
    }
    __syncthreads();
#pragma unroll
    for (int m = 0; m < 4; m++) {
#pragma unroll
        for (int r = 0; r < 4; r++) {
            const int rl = wr * 64 + m * 16 + kg * 4 + r;
            const long rr = row0 + rl;
            float S = red_s[rl][0] + red_s[rl][1] + red_s[rl][2] + red_s[rl][3];
            float Q = red_q[rl][0] + red_q[rl][1] + red_q[rl][2] + red_q[rl][3];
            float mean = S * (1.f / 256.f);
            float var = Q * (1.f / 256.f) - mean * mean;
            float inv = rsqrtf(var + 1e-5f);
            if (rr < M) {
#pragma unroll
                for (int n = 0; n < 4; n++) {
                    int col = wn * 64 + n * 16 + fr;
                    float z = acc[m][n][r] + bv[n];
                    long idx = rr * 256 + col;
                    float o = hf[idx] + fmaxf((z - mean) * inv * gv[n] + betav[n], 0.f);
                    hf[idx] = o;
                    hb[idx] = f2bf(o);
                }
            }
        }
    }
}

// ---------------- host orchestration ----------------
extern "C" void kernel_launch(void* const* d_in, const int* in_sizes, int n_in,
                              void* d_out, int out_size, void* d_ws, size_t ws_size,
                              hipStream_t stream) {
    const float* x    = (const float*)d_in[0];
    const int*   eidx = (const int*)d_in[1];
    const float* ln_g = (const float*)d_in[2];
    const float* ln_b = (const float*)d_in[3];
    const float* W1   = (const float*)d_in[4];
    const float* b1   = (const float*)d_in[5];
    const float* W2   = (const float*)d_in[6];
    const float* b2   = (const float*)d_in[7];
    const float* Wa   = (const float*)d_in[8];
    const float* ba   = (const float*)d_in[9];
    const float* Wb   = (const float*)d_in[10];
    const float* bb   = (const float*)d_in[11];
    const float* ng   = (const float*)d_in[12];
    const float* nbt  = (const float*)d_in[13];
    const float* Wd1  = (const float*)d_in[14];
    const float* bd1  = (const float*)d_in[15];
    const float* Wd2  = (const float*)d_in[16];
    const float* bd2  = (const float*)d_in[17];
    const float* outg = (const float*)d_in[18];
    const float* outbeta = (const float*)d_in[19];
    float* out = (float*)d_out;

    const int N = in_sizes[0] / 1024;  // 50000
    const int E = in_sizes[1] / 2;     // 800000
    const int* e_src = eidx;
    const int* e_dst = eidx + E;

    char* ws = (char*)d_ws;
    size_t off = 0;
    auto alloc = [&](size_t bytes) -> char* {
        char* p = ws + off;
        off += (bytes + 255) & ~(size_t)255;
        return p;
    };

    unsigned short* xln = (unsigned short*)alloc((size_t)N * 1024 * 2);
    unsigned short* zb16 = xln;                                          // N*256 bf16
    unsigned short* za   = (unsigned short*)((char*)xln + (size_t)N * 256 * 2);  // N*256 bf16
    unsigned short* delta = xln;                                         // N*1024 bf16

    unsigned short* h1 = (unsigned short*)alloc((size_t)N * 512 * 2);    // also d1
    float*          hf = (float*)alloc((size_t)N * 256 * 4);
    unsigned short* hb = (unsigned short*)alloc((size_t)N * 256 * 2);

    unsigned short* W1T  = (unsigned short*)alloc((size_t)512 * 1024 * 2);
    unsigned short* W2T  = (unsigned short*)alloc((size_t)256 * 512 * 2);
    unsigned short* WaT  = (unsigned short*)alloc((size_t)3 * 256 * 256 * 2);
    unsigned short* WbT  = (unsigned short*)alloc((size_t)3 * 256 * 256 * 2);
    unsigned short* Wd1T = (unsigned short*)alloc((size_t)512 * 256 * 2);
    unsigned short* Wd2T = (unsigned short*)alloc((size_t)1024 * 512 * 2);

    int* deg  = (int*)alloc((size_t)(N + 1) * 4);
    int* rp   = (int*)alloc((size_t)(N + 1) * 4);
    int* cur  = (int*)alloc((size_t)N * 4);
    int* bsum = (int*)alloc(64 * 4);
    int* boff = (int*)alloc(64 * 4);
    int* esrc = (int*)alloc((size_t)E * 4);

    auto cdiv = [](long a, long b) { return (int)((a + b - 1) / b); };

    k_transpose_all<<<6656, 256, 0, stream>>>(W1, W2, Wa, Wb, Wd1, Wd2,
                                              W1T, W2T, WaT, WbT, Wd1T, Wd2T);

    k_zero_i32<<<cdiv(N, 256), 256, 0, stream>>>(deg, N);
    k_hist<<<cdiv(E, 256), 256, 0, stream>>>(e_dst, E, deg);
    int nb1 = cdiv(N, 1024);  // 49
    k_scan1<<<nb1, 1024, 0, stream>>>(deg, rp, bsum, N);
    k_scan2<<<1, 64, 0, stream>>>(bsum, boff, nb1);
    k_scan3<<<cdiv(N, 256), 256, 0, stream>>>(rp, boff, cur, N, E);
    k_fill<<<cdiv(E, 256), 256, 0, stream>>>(e_src, e_dst, E, cur, esrc);

    const int ntM = cdiv(N, 128);   // 391
    const int ntM2 = cdiv(N, 256);  // 196

    // in_proj: W1 on proven 128^2 counted-vmcnt kernel (big BN=128 variant regressed, r9)
    k_ln1024_in<<<N, 256, 0, stream>>>(x, ln_g, ln_b, xln);
    k_gemm<1, 1, 0><<<ntM * 4, 256, 0, stream>>>(xln, W1T, b1, N, 1024, 512, h1, nullptr);
    k_gemm<0, 1, 1><<<ntM * 2, 256, 0, stream>>>(h1, W2T, b2, N, 512, 256, hb, hf);

    // GNN blocks
    for (int i = 0; i < 3; i++) {
        k_agg<<<cdiv(N, 4), 256, 0, stream>>>(hf, hb, rp, esrc, zb16, N);
        k_gemm<1, 1, 0><<<ntM * 2, 256, 0, stream>>>(zb16, WaT + (size_t)i * 65536, ba + (size_t)i * 256,
                                                     N, 256, 256, za, nullptr);
        k_gemm_fused_ln<<<ntM, 512, 0, stream>>>(za, WbT + (size_t)i * 65536, bb + (size_t)i * 256,
                                                 ng + (size_t)i * 256, nbt + (size_t)i * 256,
                                                 hf, hb, N);
    }

    // delta_proj + output LN: Wd2 on big 256x256 kernel (measured ~124 us vs 142, r9)
    k_gemm<1, 1, 0><<<ntM * 4, 256, 0, stream>>>(hb, Wd1T, bd1, N, 256, 512, h1, nullptr);
    k_gemm_big<0, 256><<<ntM2 * 4, 512, 0, stream>>>(h1, Wd2T, bd2, N, 512, 1024, delta);
    k_ln1024_out<<<N, 256, 0, stream>>>(x, delta, outg, outbeta, out);
}

// Round 11
// 939.398 us; speedup vs baseline: 1.0521x; 1.0386x over previous
//
#include <hip/hip_runtime.h>
#include <hip/hip_bf16.h>

#define DEVI __device__ __forceinline__

using bf16x8 = __attribute__((ext_vector_type(8))) short;   // 8 bf16 in 4 VGPRs (per guide §3)
using f32x4  = __attribute__((ext_vector_type(4))) float;

DEVI unsigned short f2bf(float f) {
    unsigned u = __builtin_bit_cast(unsigned, f);
    return (unsigned short)((u + 0x7FFFu + ((u >> 16) & 1u)) >> 16);
}
DEVI float bf2f(unsigned short h) {
    return __builtin_bit_cast(float, (unsigned)h << 16);
}

DEVI f32x4 mfma16(bf16x8 a, bf16x8 b, f32x4 c) {
    return __builtin_amdgcn_mfma_f32_16x16x32_bf16(a, b, c, 0, 0, 0);
}

// async global->LDS, 16B per lane, LDS dest = wave-uniform base + lane*16 (guide §5)
DEVI void gl16(const void* g, void* l) {
    __builtin_amdgcn_global_load_lds((const __attribute__((address_space(1))) void*)g,
                                     (__attribute__((address_space(3))) void*)l,
                                     16, 0, 0);
}

// ---------------- ALL weight transposes + bf16 cast in ONE launch ----------------
__global__ void k_transpose_all(const float* __restrict__ W1, const float* __restrict__ W2,
                                const float* __restrict__ Wa, const float* __restrict__ Wb,
                                const float* __restrict__ Wd1, const float* __restrict__ Wd2,
                                unsigned short* __restrict__ W1T, unsigned short* __restrict__ W2T,
                                unsigned short* __restrict__ WaT, unsigned short* __restrict__ WbT,
                                unsigned short* __restrict__ Wd1T, unsigned short* __restrict__ Wd2T) {
    long i = (long)blockIdx.x * 256 + threadIdx.x;
    if (i < 524288) {                      // W1T: [512][1024] <- W1 [1024][512]
        int nn = (int)(i >> 10), kk = (int)(i & 1023);
        W1T[i] = f2bf(W1[(long)kk * 512 + nn]);
        return;
    }
    i -= 524288;
    if (i < 131072) {                      // W2T: [256][512] <- W2 [512][256]
        int nn = (int)(i >> 9), kk = (int)(i & 511);
        W2T[i] = f2bf(W2[(long)kk * 256 + nn]);
        return;
    }
    i -= 131072;
    if (i < 196608) {                      // WaT: 3 x [256][256]
        int li = (int)(i & 65535), layer = (int)(i >> 16);
        int nn = li >> 8, kk = li & 255;
        WaT[i] = f2bf(Wa[(long)layer * 65536 + (long)kk * 256 + nn]);
        return;
    }
    i -= 196608;
    if (i < 196608) {                      // WbT: 3 x [256][256]
        int li = (int)(i & 65535), layer = (int)(i >> 16);
        int nn = li >> 8, kk = li & 255;
        WbT[i] = f2bf(Wb[(long)layer * 65536 + (long)kk * 256 + nn]);
        return;
    }
    i -= 196608;
    if (i < 131072) {                      // Wd1T: [512][256] <- Wd1 [256][512]
        int nn = (int)(i >> 8), kk = (int)(i & 255);
        Wd1T[i] = f2bf(Wd1[(long)kk * 512 + nn]);
        return;
    }
    i -= 131072;
    if (i < 524288) {                      // Wd2T: [1024][512] <- Wd2 [512][1024]
        int nn = (int)(i >> 9), kk = (int)(i & 511);
        Wd2T[i] = f2bf(Wd2[(long)kk * 1024 + nn]);
    }
}

// ---------------- CSR build ----------------
__global__ void k_zero_i32(int* p, int n) {
    int i = blockIdx.x * 256 + threadIdx.x;
    if (i < n) p[i] = 0;
}
__global__ void k_hist(const int* __restrict__ dst, int E, int* __restrict__ deg) {
    int i = blockIdx.x * 256 + threadIdx.x;
    if (i < E) atomicAdd(&deg[dst[i]], 1);
}
__global__ __launch_bounds__(1024)
void k_scan1(const int* __restrict__ deg, int* __restrict__ rp, int* __restrict__ bsum, int n) {
    __shared__ int sh[1024];
    int t = threadIdx.x;
    int i = blockIdx.x * 1024 + t;
    int v = (i < n) ? deg[i] : 0;
    sh[t] = v;
    __syncthreads();
    for (int off = 1; off < 1024; off <<= 1) {
        int y = (t >= off) ? sh[t - off] : 0;
        __syncthreads();
        sh[t] += y;
        __syncthreads();
    }
    if (i < n) rp[i] = sh[t] - v;            // exclusive within block
    if (t == 1023) bsum[blockIdx.x] = sh[1023];
}
__global__ __launch_bounds__(64)
void k_scan2(const int* __restrict__ bsum, int* __restrict__ boff, int nb) {  // nb <= 64
    int lane = threadIdx.x;
    int v = (lane < nb) ? bsum[lane] : 0;
    int x = v;
    for (int off = 1; off < 64; off <<= 1) {
        int y = __shfl_up(x, off);
        if (lane >= off) x += y;
    }
    if (lane < nb) boff[lane] = x - v;
}
__global__ void k_scan3(int* __restrict__ rp, const int* __restrict__ boff,
                        int* __restrict__ cur, int n, int E) {
    int i = blockIdx.x * 256 + threadIdx.x;
    if (i < n) {
        int v = rp[i] + boff[i >> 10];
        rp[i] = v;
        cur[i] = v;
    }
    if (i == 0) rp[n] = E;
}
__global__ void k_fill(const int* __restrict__ src, const int* __restrict__ dst, int E,
                       int* __restrict__ cur, int* __restrict__ esrc) {
    int i = blockIdx.x * 256 + threadIdx.x;
    if (i < E) {
        int d = dst[i];
        int p = atomicAdd(&cur[d], 1);
        esrc[p] = src[i];
    }
}

// ---------------- LayerNorm kernels ----------------
__global__ __launch_bounds__(256)
void k_ln1024_in(const float* __restrict__ x, const float* __restrict__ g,
                 const float* __restrict__ b, unsigned short* __restrict__ out) {
    const long row = blockIdx.x;
    const int tid = threadIdx.x, lane = tid & 63, wid = tid >> 6;
    float4 v = ((const float4*)(x + row * 1024))[tid];
    float s = v.x + v.y + v.z + v.w;
    float s2 = v.x * v.x + v.y * v.y + v.z * v.z + v.w * v.w;
    for (int off = 1; off < 64; off <<= 1) { s += __shfl_xor(s, off); s2 += __shfl_xor(s2, off); }
    __shared__ float red[8];
    if (lane == 0) { red[wid] = s; red[4 + wid] = s2; }
    __syncthreads();
    s = red[0] + red[1] + red[2] + red[3];
    s2 = red[4] + red[5] + red[6] + red[7];
    float m = s * (1.f / 1024.f);
    float var = s2 * (1.f / 1024.f) - m * m;
    float inv = rsqrtf(var + 1e-5f);
    float4 gv = ((const float4*)g)[tid];
    float4 bv = ((const float4*)b)[tid];
    ushort4 o = make_ushort4(f2bf((v.x - m) * inv * gv.x + bv.x),
                             f2bf((v.y - m) * inv * gv.y + bv.y),
                             f2bf((v.z - m) * inv * gv.z + bv.z),
                             f2bf((v.w - m) * inv * gv.w + bv.w));
    ((ushort4*)(out + row * 1024))[tid] = o;
}

__global__ __launch_bounds__(256)
void k_ln1024_out(const float* __restrict__ x, const unsigned short* __restrict__ delta,
                  const float* __restrict__ g, const float* __restrict__ b,
                  float* __restrict__ out) {
    const long row = blockIdx.x;
    const int tid = threadIdx.x, lane = tid & 63, wid = tid >> 6;
    float4 xv = ((const float4*)(x + row * 1024))[tid];
    ushort4 dv = ((const ushort4*)(delta + row * 1024))[tid];
    float4 v;
    v.x = xv.x + bf2f(dv.x);
    v.y = xv.y + bf2f(dv.y);
    v.z = xv.z + bf2f(dv.z);
    v.w = xv.w + bf2f(dv.w);
    float s = v.x + v.y + v.z + v.w;
    float s2 = v.x * v.x + v.y * v.y + v.z * v.z + v.w * v.w;
    for (int off = 1; off < 64; off <<= 1) { s += __shfl_xor(s, off); s2 += __shfl_xor(s2, off); }
    __shared__ float red[8];
    if (lane == 0) { red[wid] = s; red[4 + wid] = s2; }
    __syncthreads();
    s = red[0] + red[1] + red[2] + red[3];
    s2 = red[4] + red[5] + red[6] + red[7];
    float m = s * (1.f / 1024.f);
    float var = s2 * (1.f / 1024.f) - m * m;
    float inv = rsqrtf(var + 1e-5f);
    float4 gv = ((const float4*)g)[tid];
    float4 bv = ((const float4*)b)[tid];
    float4 o;
    o.x = (v.x - m) * inv * gv.x + bv.x;
    o.y = (v.y - m) * inv * gv.y + bv.y;
    o.z = (v.z - m) * inv * gv.z + bv.z;
    o.w = (v.w - m) * inv * gv.w + bv.w;
    ((float4*)(out + row * 1024))[tid] = o;
}

// ---------------- aggregation: z[dst] = h[dst] + sum_{src in-edges} h[src] ----------------
// bf16-only h (fp32 master dropped r11: residual path already bf16-dominated via hb->GEMMs;
// extra rounding damped ~10x by delta-proj weight scale before the output LN).
__global__ __launch_bounds__(256)
void k_agg(const unsigned short* __restrict__ hb,
           const int* __restrict__ rp, const int* __restrict__ esrc,
           unsigned short* __restrict__ z, int n) {
    int node = blockIdx.x * 4 + (threadIdx.x >> 6);
    if (node >= n) return;
    int lane = threadIdx.x & 63;
    ushort4 sv = ((const ushort4*)(hb + (long)node * 256))[lane];
    float a0 = bf2f(sv.x), a1 = bf2f(sv.y), a2 = bf2f(sv.z), a3 = bf2f(sv.w);
    int beg = rp[node], end = rp[node + 1];
    int e = beg;
    for (; e + 4 <= end; e += 4) {
        int s0 = esrc[e], s1 = esrc[e + 1], s2 = esrc[e + 2], s3 = esrc[e + 3];
        ushort4 v0 = ((const ushort4*)(hb + (long)s0 * 256))[lane];
        ushort4 v1 = ((const ushort4*)(hb + (long)s1 * 256))[lane];
        ushort4 v2 = ((const ushort4*)(hb + (long)s2 * 256))[lane];
        ushort4 v3 = ((const ushort4*)(hb + (long)s3 * 256))[lane];
        a0 += bf2f(v0.x) + bf2f(v1.x) + bf2f(v2.x) + bf2f(v3.x);
        a1 += bf2f(v0.y) + bf2f(v1.y) + bf2f(v2.y) + bf2f(v3.y);
        a2 += bf2f(v0.z) + bf2f(v1.z) + bf2f(v2.z) + bf2f(v3.z);
        a3 += bf2f(v0.w) + bf2f(v1.w) + bf2f(v2.w) + bf2f(v3.w);
    }
    for (; e < end; ++e) {
        int s = esrc[e];
        ushort4 hv = ((const ushort4*)(hb + (long)s * 256))[lane];
        a0 += bf2f(hv.x);
        a1 += bf2f(hv.y);
        a2 += bf2f(hv.z);
        a3 += bf2f(hv.w);
    }
    ushort4 o = make_ushort4(f2bf(a0), f2bf(a1), f2bf(a2), f2bf(a3));
    ((ushort4*)(z + (long)node * 256))[lane] = o;
}

// ---------------- bf16 MFMA GEMM: 128x128 tile (r3 schedule, proven) ----------------
template <int RELU, int WB, int WF>
__global__ __launch_bounds__(256)
void k_gemm(const unsigned short* __restrict__ A, const unsigned short* __restrict__ WT,
            const float* __restrict__ bias, int M, int K, int Nc,
            unsigned short* __restrict__ outb, float* __restrict__ outf) {
    __shared__ __align__(16) unsigned short lds_a[3 * 4096];
    __shared__ __align__(16) unsigned short lds_b[3 * 4096];
    const int tid = threadIdx.x;
    const int wid = tid >> 6, lane = tid & 63;

    const int nwg = gridDim.x;
    const int q = nwg >> 3, r8 = nwg & 7;
    const int xcd = blockIdx.x & 7, sl = blockIdx.x >> 3;
    const int bid = (xcd < r8 ? xcd * (q + 1) : r8 * (q + 1) + (xcd - r8) * q) + sl;

    const int ntN = Nc >> 7;
    const int tM = bid / ntN, tN = bid - tM * ntN;
    const long row0 = (long)tM * 128;
    const int col0 = tN << 7;
    const int wr = wid >> 1, wc = wid & 1;

    const int sr = tid >> 2;
    const int sc = (((tid & 3) ^ ((sr >> 2) & 3)) << 3);
    long ra0 = row0 + sr;       if (ra0 > (long)M - 1) ra0 = M - 1;
    long ra1 = row0 + sr + 64;  if (ra1 > (long)M - 1) ra1 = M - 1;
    const unsigned short* pa0 = A + ra0 * K + sc;
    const unsigned short* pa1 = A + ra1 * K + sc;
    const unsigned short* pb0 = WT + (long)(col0 + sr) * K + sc;
    const unsigned short* pb1 = WT + (long)(col0 + sr + 64) * K + sc;

    f32x4 zero4 = {0.f, 0.f, 0.f, 0.f};
    f32x4 acc[4][4];
#pragma unroll
    for (int m = 0; m < 4; m++)
#pragma unroll
        for (int n = 0; n < 4; n++) acc[m][n] = zero4;

    const int fr = lane & 15, kg = lane >> 4;
    const int s4 = kg ^ ((fr >> 2) & 3);
    const unsigned short* la = &lds_a[(wr * 64 + fr) * 32 + s4 * 8];
    const unsigned short* lb = &lds_b[(wc * 64 + fr) * 32 + s4 * 8];

    auto STAGE = [&](int buf, int k0) {
        const int o = buf << 12;
        gl16(pa0 + k0, &lds_a[o + wid * 512]);
        gl16(pa1 + k0, &lds_a[o + 2048 + wid * 512]);
        gl16(pb0 + k0, &lds_b[o + wid * 512]);
        gl16(pb1 + k0, &lds_b[o + 2048 + wid * 512]);
    };
    auto COMPUTE = [&](int buf) {
        const int o = buf << 12;
        bf16x8 af[4], bfr[4];
#pragma unroll
        for (int m = 0; m < 4; m++) af[m] = *(const bf16x8*)(la + o + m * 16 * 32);
#pragma unroll
        for (int n = 0; n < 4; n++) bfr[n] = *(const bf16x8*)(lb + o + n * 16 * 32);
#pragma unroll
        for (int m = 0; m < 4; m++)
#pragma unroll
            for (int n = 0; n < 4; n++) acc[m][n] = mfma16(af[m], bfr[n], acc[m][n]);
    };

    const int nsteps = K >> 5;
    STAGE(0, 0);
    STAGE(1, 32);

    int bc = 0, bs = 2;
    for (int s = 0; s < nsteps - 1; ++s) {
        asm volatile("s_waitcnt vmcnt(4)" ::: "memory");
        __builtin_amdgcn_s_barrier();
        const int k2 = (s + 2) << 5;
        if (k2 < K) STAGE(bs, k2);
        __builtin_amdgcn_sched_barrier(0);
        COMPUTE(bc);
        bc = (bc == 2) ? 0 : bc + 1;
        bs = (bs == 2) ? 0 : bs + 1;
    }
    asm volatile("s_waitcnt vmcnt(0)" ::: "memory");
    __builtin_amdgcn_s_barrier();
    COMPUTE(bc);

#pragma unroll
    for (int n = 0; n < 4; n++) {
        int col = col0 + wc * 64 + n * 16 + fr;
        float bv = bias[col];
#pragma unroll
        for (int m = 0; m < 4; m++) {
            long rb = row0 + wr * 64 + m * 16 + kg * 4;
#pragma unroll
            for (int r = 0; r < 4; r++) {
                long rr = rb + r;
                if (rr < M) {
                    float v = acc[m][n][r] + bv;
                    if (RELU) v = fmaxf(v, 0.f);
                    long idx = rr * Nc + col;
                    if (WB) outb[idx] = f2bf(v);
                    if (WF) outf[idx] = v;
                }
            }
        }
    }
}

// ---------------- big-GEMM: 256x256 tile, BK=64, 8 waves, m230-V0 2-phase schedule -------
// Measured r9/r10: Wd2 (K=512, Nc=1024) ~124 us vs 142 on k_gemm. Kept for Wd2 only.
template <int RELU, int BN>
__global__ __launch_bounds__(512, 2)
void k_gemm_big(const unsigned short* __restrict__ A, const unsigned short* __restrict__ WT,
                const float* __restrict__ bias, int M, int K, int Nc,
                unsigned short* __restrict__ outb) {
    constexpr int NB = BN / 64;                 // B staging issues per wave
    constexpr int WN = (BN == 256) ? 4 : 2;
    constexpr int MR = (BN == 256) ? 8 : 4;
    __shared__ __align__(16) unsigned short lds_a[2 * 16384];      // 2 x [256][64]
    __shared__ __align__(16) unsigned short lds_b[2 * BN * 64];    // 2 x [BN][64]

    const int tid = threadIdx.x, wid = tid >> 6, lane = tid & 63;
    const int fr = lane & 15, kg = lane >> 4;
    const int l8 = lane >> 3, l7 = lane & 7;
    const int slot_src = l7 ^ l8;               // write-side inverse of read swizzle

    const int nwg = gridDim.x;
    const int q = nwg >> 3, r8v = nwg & 7;
    const int xcd = blockIdx.x & 7, sl = blockIdx.x >> 3;
    const int bid = (xcd < r8v ? xcd * (q + 1) : r8v * (q + 1) + (xcd - r8v) * q) + sl;

    const int ntN = Nc / BN;
    const int tM = bid / ntN, tN = bid - tM * ntN;
    const long row0 = (long)tM * 256;
    const int col0 = tN * BN;
    const int wr = wid / WN, wn = wid % WN;

    const unsigned short* pa[4];
    const unsigned short* pb[4];
#pragma unroll
    for (int j = 0; j < 4; ++j) {
        long rr = row0 + j * 64 + wid * 8 + l8;
        if (rr > (long)M - 1) rr = M - 1;
        pa[j] = A + rr * K + slot_src * 8;
    }
#pragma unroll
    for (int j = 0; j < NB; ++j) {
        long rc = (long)col0 + j * 64 + wid * 8 + l8;
        pb[j] = WT + rc * K + slot_src * 8;
    }

    f32x4 zero4 = {0.f, 0.f, 0.f, 0.f};
    f32x4 acc[MR][4];
#pragma unroll
    for (int m = 0; m < MR; m++)
#pragma unroll
        for (int n = 0; n < 4; n++) acc[m][n] = zero4;

    auto STAGE = [&](int buf, int k0) {
#pragma unroll
        for (int j = 0; j < 4; ++j)
            gl16(pa[j] + k0, &lds_a[buf * 16384 + j * 4096 + wid * 512]);
#pragma unroll
        for (int j = 0; j < NB; ++j)
            gl16(pb[j] + k0, &lds_b[buf * (BN * 64) + j * 4096 + wid * 512]);
    };
    auto COMPUTE = [&](int buf) {
#pragma unroll
        for (int kh = 0; kh < 2; ++kh) {
            const int sw = ((kh * 4 + kg) ^ (fr & 7)) * 8;   // swizzled 16B slot in row
            bf16x8 af[MR], bfr[4];
#pragma unroll
            for (int m = 0; m < MR; m++)
                af[m] = *(const bf16x8*)&lds_a[buf * 16384 + (wr * (MR * 16) + m * 16 + fr) * 64 + sw];
#pragma unroll
            for (int n = 0; n < 4; n++)
                bfr[n] = *(const bf16x8*)&lds_b[buf * (BN * 64) + (wn * 64 + n * 16 + fr) * 64 + sw];
#pragma unroll
            for (int m = 0; m < MR; m++)
#pragma unroll
                for (int n = 0; n < 4; n++) acc[m][n] = mfma16(af[m], bfr[n], acc[m][n]);
        }
    };

    const int nkt = K >> 6;
    STAGE(0, 0);
    asm volatile("s_waitcnt vmcnt(0)" ::: "memory");
    __builtin_amdgcn_s_barrier();

    int buf = 0;
    for (int kt = 0; kt < nkt; ++kt) {
        if (kt + 1 < nkt) STAGE(buf ^ 1, (kt + 1) << 6);
        COMPUTE(buf);
        if (kt + 1 < nkt) {
            asm volatile("s_waitcnt vmcnt(0)" ::: "memory");
            __builtin_amdgcn_s_barrier();
        }
        buf ^= 1;
    }
    __syncthreads();   // LDS reuse for epilogue

    // ---- coalesced epilogue: 4 passes of 64 rows via lds_a ----
    float bv[4];
#pragma unroll
    for (int n = 0; n < 4; n++) bv[n] = bias[col0 + wn * 64 + n * 16 + fr];
    unsigned short* eld = lds_a;
    constexpr int ROUNDS = (64 * BN) / 4096;
#pragma unroll
    for (int p = 0; p < 4; ++p) {
        const bool part = (BN == 256) ? (wr == (p >> 1)) : (wr == p);
        if (part) {
            const int mb = (BN == 256) ? ((p & 1) * 4) : 0;
#pragma unroll
            for (int mm = 0; mm < 4; ++mm) {
                const int m = mb + mm;
                const int rl = mm * 16 + kg * 4;
#pragma unroll
                for (int n = 0; n < 4; ++n) {
                    const int cl = wn * 64 + n * 16 + fr;
#pragma unroll
                    for (int r = 0; r < 4; ++r) {
                        float v = acc[m][n][r] + bv[n];
                        if (RELU) v = fmaxf(v, 0.f);
                        eld[(rl + r) * BN + cl] = f2bf(v);
                    }
                }
            }
        }
        __syncthreads();
#pragma unroll
        for (int jj = 0; jj < ROUNDS; ++jj) {
            const int e = jj * 4096 + tid * 8;
            const int row = e / BN, col = e % BN;
            const long gr = row0 + p * 64 + row;
            if (gr < M) {
                uint4 v = *(const uint4*)&eld[e];
                *(uint4*)&outb[gr * Nc + col0 + col] = v;
            }
        }
        __syncthreads();
    }
}

// ---------------- fused layer-B GEMM + LayerNorm(256) + ReLU + residual (bf16 h) --------
__global__ __launch_bounds__(512)
void k_gemm_fused_ln(const unsigned short* __restrict__ A, const unsigned short* __restrict__ WT,
                     const float* __restrict__ bias, const float* __restrict__ g,
                     const float* __restrict__ b,
                     unsigned short* __restrict__ hb, int M) {
    __shared__ __align__(16) unsigned short lds_a[3 * 4096];   // 3 x [128][32]
    __shared__ __align__(16) unsigned short lds_b[3 * 8192];   // 3 x [256][32]
    __shared__ float red_s[128][4];
    __shared__ float red_q[128][4];
    const int tid = threadIdx.x, wid = tid >> 6, lane = tid & 63;
    const int fr = lane & 15, kg = lane >> 4;

    const int nwg = gridDim.x;
    const int q = nwg >> 3, r8 = nwg & 7;
    const int xcd = blockIdx.x & 7, sl = blockIdx.x >> 3;
    const int bid = (xcd < r8 ? xcd * (q + 1) : r8 * (q + 1) + (xcd - r8) * q) + sl;
    const long row0 = (long)bid * 128;
    const int wr = wid >> 2, wn = wid & 3;

    const int srow = lane >> 2, slot = lane & 3;
    long ar = row0 + wid * 16 + srow; if (ar > (long)M - 1) ar = M - 1;
    const unsigned short* pa  = A + ar * 256 + slot * 8;
    const unsigned short* pb0 = WT + (long)(wid * 16 + srow) * 256 + slot * 8;
    const unsigned short* pb1 = WT + (long)(128 + wid * 16 + srow) * 256 + slot * 8;

    f32x4 zero4 = {0.f, 0.f, 0.f, 0.f};
    f32x4 acc[4][4];
#pragma unroll
    for (int m = 0; m < 4; m++)
#pragma unroll
        for (int n = 0; n < 4; n++) acc[m][n] = zero4;

    auto STAGE = [&](int buf, int k0) {
        gl16(pa + k0, &lds_a[buf * 4096 + wid * 512]);
        gl16(pb0 + k0, &lds_b[buf * 8192 + wid * 512]);
        gl16(pb1 + k0, &lds_b[buf * 8192 + 4096 + wid * 512]);
    };
    auto COMPUTE = [&](int buf) {
        bf16x8 af[4], bfr[4];
#pragma unroll
        for (int m = 0; m < 4; m++)
            af[m] = *(const bf16x8*)&lds_a[buf * 4096 + (wr * 64 + m * 16 + fr) * 32 + kg * 8];
#pragma unroll
        for (int n = 0; n < 4; n++)
            bfr[n] = *(const bf16x8*)&lds_b[buf * 8192 + (wn * 64 + n * 16 + fr) * 32 + kg * 8];
#pragma unroll
        for (int m = 0; m < 4; m++)
#pragma unroll
            for (int n = 0; n < 4; n++) acc[m][n] = mfma16(af[m], bfr[n], acc[m][n]);
    };

    STAGE(0, 0);
    STAGE(1, 32);
    int bc = 0, bs = 2;
    for (int s = 0; s < 7; ++s) {
        asm volatile("s_waitcnt vmcnt(3)" ::: "memory");
        __builtin_amdgcn_s_barrier();
        const int k2 = (s + 2) << 5;
        if (k2 < 256) STAGE(bs, k2);
        __builtin_amdgcn_sched_barrier(0);
        COMPUTE(bc);
        bc = (bc == 2) ? 0 : bc + 1;
        bs = (bs == 2) ? 0 : bs + 1;
    }
    asm volatile("s_waitcnt vmcnt(0)" ::: "memory");
    __builtin_amdgcn_s_barrier();
    COMPUTE(bc);

    float bv[4], gv[4], betav[4];
#pragma unroll
    for (int n = 0; n < 4; n++) {
        int col = wn * 64 + n * 16 + fr;
        bv[n] = bias[col];
        gv[n] = g[col];
        betav[n] = b[col];
    }
#pragma unroll
    for (int m = 0; m < 4; m++) {
#pragma unroll
        for (int r = 0; r < 4; r++) {
            float s = 0.f, q2 = 0.f;
#pragma unroll
            for (int n = 0; n < 4; n++) {
                float z = acc[m][n][r] + bv[n];
                s += z;
                q2 += z * z;
            }
#pragma unroll
            for (int off = 1; off < 16; off <<= 1) {
                s += __shfl_xor(s, off);
                q2 += __shfl_xor(q2, off);
            }
            if (fr == 0) {
                int rl = wr * 64 + m * 16 + kg * 4 + r;
                red_s[rl][wn] = s;
                red_q[rl][wn] = q2;
            }
        }
    }
    __syncthreads();
#pragma unroll
    for (int m = 0; m < 4; m++) {
#pragma unroll
        for (int r = 0; r < 4; r++) {
            const int rl = wr * 64 + m * 16 + kg * 4 + r;
            const long rr = row0 + rl;
            float S = red_s[rl][0] + red_s[rl][1] + red_s[rl][2] + red_s[rl][3];
            float Q = red_q[rl][0] + red_q[rl][1] + red_q[rl][2] + red_q[rl][3];
            float mean = S * (1.f / 256.f);
            float var = Q * (1.f / 256.f) - mean * mean;
            float inv = rsqrtf(var + 1e-5f);
            if (rr < M) {
#pragma unroll
                for (int n = 0; n < 4; n++) {
                    int col = wn * 64 + n * 16 + fr;
                    float z = acc[m][n][r] + bv[n];
                    long idx = rr * 256 + col;
                    float o = bf2f(hb[idx]) + fmaxf((z - mean) * inv * gv[n] + betav[n], 0.f);
                    hb[idx] = f2bf(o);
                }
            }
        }
    }
}

// ---------------- host orchestration ----------------
extern "C" void kernel_launch(void* const* d_in, const int* in_sizes, int n_in,
                              void* d_out, int out_size, void* d_ws, size_t ws_size,
                              hipStream_t stream) {
    const float* x    = (const float*)d_in[0];
    const int*   eidx = (const int*)d_in[1];
    const float* ln_g = (const float*)d_in[2];
    const float* ln_b = (const float*)d_in[3];
    const float* W1   = (const float*)d_in[4];
    const float* b1   = (const float*)d_in[5];
    const float* W2   = (const float*)d_in[6];
    const float* b2   = (const float*)d_in[7];
    const float* Wa   = (const float*)d_in[8];
    const float* ba   = (const float*)d_in[9];
    const float* Wb   = (const float*)d_in[10];
    const float* bb   = (const float*)d_in[11];
    const float* ng   = (const float*)d_in[12];
    const float* nbt  = (const float*)d_in[13];
    const float* Wd1  = (const float*)d_in[14];
    const float* bd1  = (const float*)d_in[15];
    const float* Wd2  = (const float*)d_in[16];
    const float* bd2  = (const float*)d_in[17];
    const float* outg = (const float*)d_in[18];
    const float* outbeta = (const float*)d_in[19];
    float* out = (float*)d_out;

    const int N = in_sizes[0] / 1024;  // 50000
    const int E = in_sizes[1] / 2;     // 800000
    const int* e_src = eidx;
    const int* e_dst = eidx + E;

    char* ws = (char*)d_ws;
    size_t off = 0;
    auto alloc = [&](size_t bytes) -> char* {
        char* p = ws + off;
        off += (bytes + 255) & ~(size_t)255;
        return p;
    };

    unsigned short* xln = (unsigned short*)alloc((size_t)N * 1024 * 2);
    unsigned short* zb16 = xln;                                          // N*256 bf16
    unsigned short* za   = (unsigned short*)((char*)xln + (size_t)N * 256 * 2);  // N*256 bf16
    unsigned short* delta = xln;                                         // N*1024 bf16

    unsigned short* h1 = (unsigned short*)alloc((size_t)N * 512 * 2);    // also d1
    unsigned short* hb = (unsigned short*)alloc((size_t)N * 256 * 2);

    unsigned short* W1T  = (unsigned short*)alloc((size_t)512 * 1024 * 2);
    unsigned short* W2T  = (unsigned short*)alloc((size_t)256 * 512 * 2);
    unsigned short* WaT  = (unsigned short*)alloc((size_t)3 * 256 * 256 * 2);
    unsigned short* WbT  = (unsigned short*)alloc((size_t)3 * 256 * 256 * 2);
    unsigned short* Wd1T = (unsigned short*)alloc((size_t)512 * 256 * 2);
    unsigned short* Wd2T = (unsigned short*)alloc((size_t)1024 * 512 * 2);

    int* deg  = (int*)alloc((size_t)(N + 1) * 4);
    int* rp   = (int*)alloc((size_t)(N + 1) * 4);
    int* cur  = (int*)alloc((size_t)N * 4);
    int* bsum = (int*)alloc(64 * 4);
    int* boff = (int*)alloc(64 * 4);
    int* esrc = (int*)alloc((size_t)E * 4);

    auto cdiv = [](long a, long b) { return (int)((a + b - 1) / b); };

    k_transpose_all<<<6656, 256, 0, stream>>>(W1, W2, Wa, Wb, Wd1, Wd2,
                                              W1T, W2T, WaT, WbT, Wd1T, Wd2T);

    k_zero_i32<<<cdiv(N, 256), 256, 0, stream>>>(deg, N);
    k_hist<<<cdiv(E, 256), 256, 0, stream>>>(e_dst, E, deg);
    int nb1 = cdiv(N, 1024);  // 49
    k_scan1<<<nb1, 1024, 0, stream>>>(deg, rp, bsum, N);
    k_scan2<<<1, 64, 0, stream>>>(bsum, boff, nb1);
    k_scan3<<<cdiv(N, 256), 256, 0, stream>>>(rp, boff, cur, N, E);
    k_fill<<<cdiv(E, 256), 256, 0, stream>>>(e_src, e_dst, E, cur, esrc);

    const int ntM = cdiv(N, 128);   // 391
    const int ntM2 = cdiv(N, 256);  // 196

    // in_proj
    k_ln1024_in<<<N, 256, 0, stream>>>(x, ln_g, ln_b, xln);
    k_gemm<1, 1, 0><<<ntM * 4, 256, 0, stream>>>(xln, W1T, b1, N, 1024, 512, h1, nullptr);
    k_gemm<0, 1, 0><<<ntM * 2, 256, 0, stream>>>(h1, W2T, b2, N, 512, 256, hb, nullptr);

    // GNN blocks (bf16-only h)
    for (int i = 0; i < 3; i++) {
        k_agg<<<cdiv(N, 4), 256, 0, stream>>>(hb, rp, esrc, zb16, N);
        k_gemm<1, 1, 0><<<ntM * 2, 256, 0, stream>>>(zb16, WaT + (size_t)i * 65536, ba + (size_t)i * 256,
                                                     N, 256, 256, za, nullptr);
        k_gemm_fused_ln<<<ntM, 512, 0, stream>>>(za, WbT + (size_t)i * 65536, bb + (size_t)i * 256,
                                                 ng + (size_t)i * 256, nbt + (size_t)i * 256,
                                                 hb, N);
    }

    // delta_proj + output LN
    k_gemm<1, 1, 0><<<ntM * 4, 256, 0, stream>>>(hb, Wd1T, bd1, N, 256, 512, h1, nullptr);
    k_gemm_big<0, 256><<<ntM2 * 4, 512, 0, stream>>>(h1, Wd2T, bd2, N, 512, 1024, delta);
    k_ln1024_out<<<N, 256, 0, stream>>>(x, delta, outg, outbeta, out);
}

// Round 12
// 898.452 us; speedup vs baseline: 1.1000x; 1.0456x over previous
//
#include <hip/hip_runtime.h>
#include <hip/hip_bf16.h>

#define DEVI __device__ __forceinline__

using bf16x8 = __attribute__((ext_vector_type(8))) short;   // 8 bf16 in 4 VGPRs (per guide §3)
using f32x4  = __attribute__((ext_vector_type(4))) float;

DEVI unsigned short f2bf(float f) {
    unsigned u = __builtin_bit_cast(unsigned, f);
    return (unsigned short)((u + 0x7FFFu + ((u >> 16) & 1u)) >> 16);
}
DEVI float bf2f(unsigned short h) {
    return __builtin_bit_cast(float, (unsigned)h << 16);
}

DEVI f32x4 mfma16(bf16x8 a, bf16x8 b, f32x4 c) {
    return __builtin_amdgcn_mfma_f32_16x16x32_bf16(a, b, c, 0, 0, 0);
}

// async global->LDS, 16B per lane, LDS dest = wave-uniform base + lane*16 (guide §5)
DEVI void gl16(const void* g, void* l) {
    __builtin_amdgcn_global_load_lds((const __attribute__((address_space(1))) void*)g,
                                     (__attribute__((address_space(3))) void*)l,
                                     16, 0, 0);
}

// ---------------- ALL weight transposes + bf16 cast in ONE launch ----------------
__global__ void k_transpose_all(const float* __restrict__ W1, const float* __restrict__ W2,
                                const float* __restrict__ Wa, const float* __restrict__ Wb,
                                const float* __restrict__ Wd1, const float* __restrict__ Wd2,
                                unsigned short* __restrict__ W1T, unsigned short* __restrict__ W2T,
                                unsigned short* __restrict__ WaT, unsigned short* __restrict__ WbT,
                                unsigned short* __restrict__ Wd1T, unsigned short* __restrict__ Wd2T) {
    long i = (long)blockIdx.x * 256 + threadIdx.x;
    if (i < 524288) {                      // W1T: [512][1024] <- W1 [1024][512]
        int nn = (int)(i >> 10), kk = (int)(i & 1023);
        W1T[i] = f2bf(W1[(long)kk * 512 + nn]);
        return;
    }
    i -= 524288;
    if (i < 131072) {                      // W2T: [256][512] <- W2 [512][256]
        int nn = (int)(i >> 9), kk = (int)(i & 511);
        W2T[i] = f2bf(W2[(long)kk * 256 + nn]);
        return;
    }
    i -= 131072;
    if (i < 196608) {                      // WaT: 3 x [256][256]
        int li = (int)(i & 65535), layer = (int)(i >> 16);
        int nn = li >> 8, kk = li & 255;
        WaT[i] = f2bf(Wa[(long)layer * 65536 + (long)kk * 256 + nn]);
        return;
    }
    i -= 196608;
    if (i < 196608) {                      // WbT: 3 x [256][256]
        int li = (int)(i & 65535), layer = (int)(i >> 16);
        int nn = li >> 8, kk = li & 255;
        WbT[i] = f2bf(Wb[(long)layer * 65536 + (long)kk * 256 + nn]);
        return;
    }
    i -= 196608;
    if (i < 131072) {                      // Wd1T: [512][256] <- Wd1 [256][512]
        int nn = (int)(i >> 8), kk = (int)(i & 255);
        Wd1T[i] = f2bf(Wd1[(long)kk * 512 + nn]);
        return;
    }
    i -= 131072;
    if (i < 524288) {                      // Wd2T: [1024][512] <- Wd2 [512][1024]
        int nn = (int)(i >> 9), kk = (int)(i & 511);
        Wd2T[i] = f2bf(Wd2[(long)kk * 1024 + nn]);
    }
}

// ---------------- CSR build ----------------
__global__ void k_zero_i32(int* p, int n) {
    int i = blockIdx.x * 256 + threadIdx.x;
    if (i < n) p[i] = 0;
}
__global__ void k_hist(const int* __restrict__ dst, int E, int* __restrict__ deg) {
    int i = blockIdx.x * 256 + threadIdx.x;
    if (i < E) atomicAdd(&deg[dst[i]], 1);
}
__global__ __launch_bounds__(1024)
void k_scan1(const int* __restrict__ deg, int* __restrict__ rp, int* __restrict__ bsum, int n) {
    __shared__ int sh[1024];
    int t = threadIdx.x;
    int i = blockIdx.x * 1024 + t;
    int v = (i < n) ? deg[i] : 0;
    sh[t] = v;
    __syncthreads();
    for (int off = 1; off < 1024; off <<= 1) {
        int y = (t >= off) ? sh[t - off] : 0;
        __syncthreads();
        sh[t] += y;
        __syncthreads();
    }
    if (i < n) rp[i] = sh[t] - v;            // exclusive within block
    if (t == 1023) bsum[blockIdx.x] = sh[1023];
}
__global__ __launch_bounds__(64)
void k_scan2(const int* __restrict__ bsum, int* __restrict__ boff, int nb) {  // nb <= 64
    int lane = threadIdx.x;
    int v = (lane < nb) ? bsum[lane] : 0;
    int x = v;
    for (int off = 1; off < 64; off <<= 1) {
        int y = __shfl_up(x, off);
        if (lane >= off) x += y;
    }
    if (lane < nb) boff[lane] = x - v;
}
__global__ void k_scan3(int* __restrict__ rp, const int* __restrict__ boff,
                        int* __restrict__ cur, int n, int E) {
    int i = blockIdx.x * 256 + threadIdx.x;
    if (i < n) {
        int v = rp[i] + boff[i >> 10];
        rp[i] = v;
        cur[i] = v;
    }
    if (i == 0) rp[n] = E;
}
__global__ void k_fill(const int* __restrict__ src, const int* __restrict__ dst, int E,
                       int* __restrict__ cur, int* __restrict__ esrc) {
    int i = blockIdx.x * 256 + threadIdx.x;
    if (i < E) {
        int d = dst[i];
        int p = atomicAdd(&cur[d], 1);
        esrc[p] = src[i];
    }
}

// ---------------- LayerNorm kernels ----------------
__global__ __launch_bounds__(256)
void k_ln1024_in(const float* __restrict__ x, const float* __restrict__ g,
                 const float* __restrict__ b, unsigned short* __restrict__ out) {
    const long row = blockIdx.x;
    const int tid = threadIdx.x, lane = tid & 63, wid = tid >> 6;
    float4 v = ((const float4*)(x + row * 1024))[tid];
    float s = v.x + v.y + v.z + v.w;
    float s2 = v.x * v.x + v.y * v.y + v.z * v.z + v.w * v.w;
    for (int off = 1; off < 64; off <<= 1) { s += __shfl_xor(s, off); s2 += __shfl_xor(s2, off); }
    __shared__ float red[8];
    if (lane == 0) { red[wid] = s; red[4 + wid] = s2; }
    __syncthreads();
    s = red[0] + red[1] + red[2] + red[3];
    s2 = red[4] + red[5] + red[6] + red[7];
    float m = s * (1.f / 1024.f);
    float var = s2 * (1.f / 1024.f) - m * m;
    float inv = rsqrtf(var + 1e-5f);
    float4 gv = ((const float4*)g)[tid];
    float4 bv = ((const float4*)b)[tid];
    ushort4 o = make_ushort4(f2bf((v.x - m) * inv * gv.x + bv.x),
                             f2bf((v.y - m) * inv * gv.y + bv.y),
                             f2bf((v.z - m) * inv * gv.z + bv.z),
                             f2bf((v.w - m) * inv * gv.w + bv.w));
    ((ushort4*)(out + row * 1024))[tid] = o;
}

__global__ __launch_bounds__(256)
void k_ln1024_out(const float* __restrict__ x, const unsigned short* __restrict__ delta,
                  const float* __restrict__ g, const float* __restrict__ b,
                  float* __restrict__ out) {
    const long row = blockIdx.x;
    const int tid = threadIdx.x, lane = tid & 63, wid = tid >> 6;
    float4 xv = ((const float4*)(x + row * 1024))[tid];
    ushort4 dv = ((const ushort4*)(delta + row * 1024))[tid];
    float4 v;
    v.x = xv.x + bf2f(dv.x);
    v.y = xv.y + bf2f(dv.y);
    v.z = xv.z + bf2f(dv.z);
    v.w = xv.w + bf2f(dv.w);
    float s = v.x + v.y + v.z + v.w;
    float s2 = v.x * v.x + v.y * v.y + v.z * v.z + v.w * v.w;
    for (int off = 1; off < 64; off <<= 1) { s += __shfl_xor(s, off); s2 += __shfl_xor(s2, off); }
    __shared__ float red[8];
    if (lane == 0) { red[wid] = s; red[4 + wid] = s2; }
    __syncthreads();
    s = red[0] + red[1] + red[2] + red[3];
    s2 = red[4] + red[5] + red[6] + red[7];
    float m = s * (1.f / 1024.f);
    float var = s2 * (1.f / 1024.f) - m * m;
    float inv = rsqrtf(var + 1e-5f);
    float4 gv = ((const float4*)g)[tid];
    float4 bv = ((const float4*)b)[tid];
    float4 o;
    o.x = (v.x - m) * inv * gv.x + bv.x;
    o.y = (v.y - m) * inv * gv.y + bv.y;
    o.z = (v.z - m) * inv * gv.z + bv.z;
    o.w = (v.w - m) * inv * gv.w + bv.w;
    ((float4*)(out + row * 1024))[tid] = o;
}

// ---------------- aggregation: z[dst] = h[dst] + sum_{src in-edges} h[src] ----------------
__global__ __launch_bounds__(256)
void k_agg(const unsigned short* __restrict__ hb,
           const int* __restrict__ rp, const int* __restrict__ esrc,
           unsigned short* __restrict__ z, int n) {
    int node = blockIdx.x * 4 + (threadIdx.x >> 6);
    if (node >= n) return;
    int lane = threadIdx.x & 63;
    ushort4 sv = ((const ushort4*)(hb + (long)node * 256))[lane];
    float a0 = bf2f(sv.x), a1 = bf2f(sv.y), a2 = bf2f(sv.z), a3 = bf2f(sv.w);
    int beg = rp[node], end = rp[node + 1];
    int e = beg;
    for (; e + 4 <= end; e += 4) {
        int s0 = esrc[e], s1 = esrc[e + 1], s2 = esrc[e + 2], s3 = esrc[e + 3];
        ushort4 v0 = ((const ushort4*)(hb + (long)s0 * 256))[lane];
        ushort4 v1 = ((const ushort4*)(hb + (long)s1 * 256))[lane];
        ushort4 v2 = ((const ushort4*)(hb + (long)s2 * 256))[lane];
        ushort4 v3 = ((const ushort4*)(hb + (long)s3 * 256))[lane];
        a0 += bf2f(v0.x) + bf2f(v1.x) + bf2f(v2.x) + bf2f(v3.x);
        a1 += bf2f(v0.y) + bf2f(v1.y) + bf2f(v2.y) + bf2f(v3.y);
        a2 += bf2f(v0.z) + bf2f(v1.z) + bf2f(v2.z) + bf2f(v3.z);
        a3 += bf2f(v0.w) + bf2f(v1.w) + bf2f(v2.w) + bf2f(v3.w);
    }
    for (; e < end; ++e) {
        int s = esrc[e];
        ushort4 hv = ((const ushort4*)(hb + (long)s * 256))[lane];
        a0 += bf2f(hv.x);
        a1 += bf2f(hv.y);
        a2 += bf2f(hv.z);
        a3 += bf2f(hv.w);
    }
    ushort4 o = make_ushort4(f2bf(a0), f2bf(a1), f2bf(a2), f2bf(a3));
    ((ushort4*)(z + (long)node * 256))[lane] = o;
}

// ---------------- bf16 MFMA GEMM: 128x128 tile (r3 schedule, proven) ----------------
// Kept for K=256 shapes (Wa, Wd1) where the big kernel's nkt=4 prologue fraction is
// unvalidated; K>=512 shapes moved to k_gemm_big (measured faster, r9-r12).
template <int RELU, int WB, int WF>
__global__ __launch_bounds__(256)
void k_gemm(const unsigned short* __restrict__ A, const unsigned short* __restrict__ WT,
            const float* __restrict__ bias, int M, int K, int Nc,
            unsigned short* __restrict__ outb, float* __restrict__ outf) {
    __shared__ __align__(16) unsigned short lds_a[3 * 4096];
    __shared__ __align__(16) unsigned short lds_b[3 * 4096];
    const int tid = threadIdx.x;
    const int wid = tid >> 6, lane = tid & 63;

    const int nwg = gridDim.x;
    const int q = nwg >> 3, r8 = nwg & 7;
    const int xcd = blockIdx.x & 7, sl = blockIdx.x >> 3;
    const int bid = (xcd < r8 ? xcd * (q + 1) : r8 * (q + 1) + (xcd - r8) * q) + sl;

    const int ntN = Nc >> 7;
    const int tM = bid / ntN, tN = bid - tM * ntN;
    const long row0 = (long)tM * 128;
    const int col0 = tN << 7;
    const int wr = wid >> 1, wc = wid & 1;

    const int sr = tid >> 2;
    const int sc = (((tid & 3) ^ ((sr >> 2) & 3)) << 3);
    long ra0 = row0 + sr;       if (ra0 > (long)M - 1) ra0 = M - 1;
    long ra1 = row0 + sr + 64;  if (ra1 > (long)M - 1) ra1 = M - 1;
    const unsigned short* pa0 = A + ra0 * K + sc;
    const unsigned short* pa1 = A + ra1 * K + sc;
    const unsigned short* pb0 = WT + (long)(col0 + sr) * K + sc;
    const unsigned short* pb1 = WT + (long)(col0 + sr + 64) * K + sc;

    f32x4 zero4 = {0.f, 0.f, 0.f, 0.f};
    f32x4 acc[4][4];
#pragma unroll
    for (int m = 0; m < 4; m++)
#pragma unroll
        for (int n = 0; n < 4; n++) acc[m][n] = zero4;

    const int fr = lane & 15, kg = lane >> 4;
    const int s4 = kg ^ ((fr >> 2) & 3);
    const unsigned short* la = &lds_a[(wr * 64 + fr) * 32 + s4 * 8];
    const unsigned short* lb = &lds_b[(wc * 64 + fr) * 32 + s4 * 8];

    auto STAGE = [&](int buf, int k0) {
        const int o = buf << 12;
        gl16(pa0 + k0, &lds_a[o + wid * 512]);
        gl16(pa1 + k0, &lds_a[o + 2048 + wid * 512]);
        gl16(pb0 + k0, &lds_b[o + wid * 512]);
        gl16(pb1 + k0, &lds_b[o + 2048 + wid * 512]);
    };
    auto COMPUTE = [&](int buf) {
        const int o = buf << 12;
        bf16x8 af[4], bfr[4];
#pragma unroll
        for (int m = 0; m < 4; m++) af[m] = *(const bf16x8*)(la + o + m * 16 * 32);
#pragma unroll
        for (int n = 0; n < 4; n++) bfr[n] = *(const bf16x8*)(lb + o + n * 16 * 32);
#pragma unroll
        for (int m = 0; m < 4; m++)
#pragma unroll
            for (int n = 0; n < 4; n++) acc[m][n] = mfma16(af[m], bfr[n], acc[m][n]);
    };

    const int nsteps = K >> 5;
    STAGE(0, 0);
    STAGE(1, 32);

    int bc = 0, bs = 2;
    for (int s = 0; s < nsteps - 1; ++s) {
        asm volatile("s_waitcnt vmcnt(4)" ::: "memory");
        __builtin_amdgcn_s_barrier();
        const int k2 = (s + 2) << 5;
        if (k2 < K) STAGE(bs, k2);
        __builtin_amdgcn_sched_barrier(0);
        COMPUTE(bc);
        bc = (bc == 2) ? 0 : bc + 1;
        bs = (bs == 2) ? 0 : bs + 1;
    }
    asm volatile("s_waitcnt vmcnt(0)" ::: "memory");
    __builtin_amdgcn_s_barrier();
    COMPUTE(bc);

#pragma unroll
    for (int n = 0; n < 4; n++) {
        int col = col0 + wc * 64 + n * 16 + fr;
        float bv = bias[col];
#pragma unroll
        for (int m = 0; m < 4; m++) {
            long rb = row0 + wr * 64 + m * 16 + kg * 4;
#pragma unroll
            for (int r = 0; r < 4; r++) {
                long rr = rb + r;
                if (rr < M) {
                    float v = acc[m][n][r] + bv;
                    if (RELU) v = fmaxf(v, 0.f);
                    long idx = rr * Nc + col;
                    if (WB) outb[idx] = f2bf(v);
                    if (WF) outf[idx] = v;
                }
            }
        }
    }
}

// ---------------- big-GEMM: 256x256 tile, BK=64, 8 waves, m230-V0 2-phase schedule -------
// Measured: Wd2 (K=512) 142->124 us vs k_gemm (r9/r10). Mechanism: 64 MFMA/wave per
// drain-point amortizes the per-K-tile vmcnt(0). Now also W1 (K=1024, 392-block grid,
// same per-K-tile structure) and W2 (K=512, identical to Wd2's K config).
template <int RELU, int BN>
__global__ __launch_bounds__(512, 2)
void k_gemm_big(const unsigned short* __restrict__ A, const unsigned short* __restrict__ WT,
                const float* __restrict__ bias, int M, int K, int Nc,
                unsigned short* __restrict__ outb) {
    constexpr int NB = BN / 64;                 // B staging issues per wave
    constexpr int WN = (BN == 256) ? 4 : 2;
    constexpr int MR = (BN == 256) ? 8 : 4;
    __shared__ __align__(16) unsigned short lds_a[2 * 16384];      // 2 x [256][64]
    __shared__ __align__(16) unsigned short lds_b[2 * BN * 64];    // 2 x [BN][64]

    const int tid = threadIdx.x, wid = tid >> 6, lane = tid & 63;
    const int fr = lane & 15, kg = lane >> 4;
    const int l8 = lane >> 3, l7 = lane & 7;
    const int slot_src = l7 ^ l8;               // write-side inverse of read swizzle

    const int nwg = gridDim.x;
    const int q = nwg >> 3, r8v = nwg & 7;
    const int xcd = blockIdx.x & 7, sl = blockIdx.x >> 3;
    const int bid = (xcd < r8v ? xcd * (q + 1) : r8v * (q + 1) + (xcd - r8v) * q) + sl;

    const int ntN = Nc / BN;
    const int tM = bid / ntN, tN = bid - tM * ntN;
    const long row0 = (long)tM * 256;
    const int col0 = tN * BN;
    const int wr = wid / WN, wn = wid % WN;

    const unsigned short* pa[4];
    const unsigned short* pb[4];
#pragma unroll
    for (int j = 0; j < 4; ++j) {
        long rr = row0 + j * 64 + wid * 8 + l8;
        if (rr > (long)M - 1) rr = M - 1;
        pa[j] = A + rr * K + slot_src * 8;
    }
#pragma unroll
    for (int j = 0; j < NB; ++j) {
        long rc = (long)col0 + j * 64 + wid * 8 + l8;
        pb[j] = WT + rc * K + slot_src * 8;
    }

    f32x4 zero4 = {0.f, 0.f, 0.f, 0.f};
    f32x4 acc[MR][4];
#pragma unroll
    for (int m = 0; m < MR; m++)
#pragma unroll
        for (int n = 0; n < 4; n++) acc[m][n] = zero4;

    auto STAGE = [&](int buf, int k0) {
#pragma unroll
        for (int j = 0; j < 4; ++j)
            gl16(pa[j] + k0, &lds_a[buf * 16384 + j * 4096 + wid * 512]);
#pragma unroll
        for (int j = 0; j < NB; ++j)
            gl16(pb[j] + k0, &lds_b[buf * (BN * 64) + j * 4096 + wid * 512]);
    };
    auto COMPUTE = [&](int buf) {
#pragma unroll
        for (int kh = 0; kh < 2; ++kh) {
            const int sw = ((kh * 4 + kg) ^ (fr & 7)) * 8;   // swizzled 16B slot in row
            bf16x8 af[MR], bfr[4];
#pragma unroll
            for (int m = 0; m < MR; m++)
                af[m] = *(const bf16x8*)&lds_a[buf * 16384 + (wr * (MR * 16) + m * 16 + fr) * 64 + sw];
#pragma unroll
            for (int n = 0; n < 4; n++)
                bfr[n] = *(const bf16x8*)&lds_b[buf * (BN * 64) + (wn * 64 + n * 16 + fr) * 64 + sw];
#pragma unroll
            for (int m = 0; m < MR; m++)
#pragma unroll
                for (int n = 0; n < 4; n++) acc[m][n] = mfma16(af[m], bfr[n], acc[m][n]);
        }
    };

    const int nkt = K >> 6;
    STAGE(0, 0);
    asm volatile("s_waitcnt vmcnt(0)" ::: "memory");
    __builtin_amdgcn_s_barrier();

    int buf = 0;
    for (int kt = 0; kt < nkt; ++kt) {
        if (kt + 1 < nkt) STAGE(buf ^ 1, (kt + 1) << 6);
        COMPUTE(buf);
        if (kt + 1 < nkt) {
            asm volatile("s_waitcnt vmcnt(0)" ::: "memory");
            __builtin_amdgcn_s_barrier();
        }
        buf ^= 1;
    }
    __syncthreads();   // LDS reuse for epilogue

    // ---- coalesced epilogue: 4 passes of 64 rows via lds_a ----
    float bv[4];
#pragma unroll
    for (int n = 0; n < 4; n++) bv[n] = bias[col0 + wn * 64 + n * 16 + fr];
    unsigned short* eld = lds_a;
    constexpr int ROUNDS = (64 * BN) / 4096;
#pragma unroll
    for (int p = 0; p < 4; ++p) {
        const bool part = (BN == 256) ? (wr == (p >> 1)) : (wr == p);
        if (part) {
            const int mb = (BN == 256) ? ((p & 1) * 4) : 0;
#pragma unroll
            for (int mm = 0; mm < 4; ++mm) {
                const int m = mb + mm;
                const int rl = mm * 16 + kg * 4;
#pragma unroll
                for (int n = 0; n < 4; ++n) {
                    const int cl = wn * 64 + n * 16 + fr;
#pragma unroll
                    for (int r = 0; r < 4; ++r) {
                        float v = acc[m][n][r] + bv[n];
                        if (RELU) v = fmaxf(v, 0.f);
                        eld[(rl + r) * BN + cl] = f2bf(v);
                    }
                }
            }
        }
        __syncthreads();
#pragma unroll
        for (int jj = 0; jj < ROUNDS; ++jj) {
            const int e = jj * 4096 + tid * 8;
            const int row = e / BN, col = e % BN;
            const long gr = row0 + p * 64 + row;
            if (gr < M) {
                uint4 v = *(const uint4*)&eld[e];
                *(uint4*)&outb[gr * Nc + col0 + col] = v;
            }
        }
        __syncthreads();
    }
}

// ---------------- fused layer-B GEMM + LayerNorm(256) + ReLU + residual (bf16 h) --------
__global__ __launch_bounds__(512)
void k_gemm_fused_ln(const unsigned short* __restrict__ A, const unsigned short* __restrict__ WT,
                     const float* __restrict__ bias, const float* __restrict__ g,
                     const float* __restrict__ b,
                     unsigned short* __restrict__ hb, int M) {
    __shared__ __align__(16) unsigned short lds_a[3 * 4096];   // 3 x [128][32]
    __shared__ __align__(16) unsigned short lds_b[3 * 8192];   // 3 x [256][32]
    __shared__ float red_s[128][4];
    __shared__ float red_q[128][4];
    const int tid = threadIdx.x, wid = tid >> 6, lane = tid & 63;
    const int fr = lane & 15, kg = lane >> 4;

    const int nwg = gridDim.x;
    const int q = nwg >> 3, r8 = nwg & 7;
    const int xcd = blockIdx.x & 7, sl = blockIdx.x >> 3;
    const int bid = (xcd < r8 ? xcd * (q + 1) : r8 * (q + 1) + (xcd - r8) * q) + sl;
    const long row0 = (long)bid * 128;
    const int wr = wid >> 2, wn = wid & 3;

    const int srow = lane >> 2, slot = lane & 3;
    long ar = row0 + wid * 16 + srow; if (ar > (long)M - 1) ar = M - 1;
    const unsigned short* pa  = A + ar * 256 + slot * 8;
    const unsigned short* pb0 = WT + (long)(wid * 16 + srow) * 256 + slot * 8;
    const unsigned short* pb1 = WT + (long)(128 + wid * 16 + srow) * 256 + slot * 8;

    f32x4 zero4 = {0.f, 0.f, 0.f, 0.f};
    f32x4 acc[4][4];
#pragma unroll
    for (int m = 0; m < 4; m++)
#pragma unroll
        for (int n = 0; n < 4; n++) acc[m][n] = zero4;

    auto STAGE = [&](int buf, int k0) {
        gl16(pa + k0, &lds_a[buf * 4096 + wid * 512]);
        gl16(pb0 + k0, &lds_b[buf * 8192 + wid * 512]);
        gl16(pb1 + k0, &lds_b[buf * 8192 + 4096 + wid * 512]);
    };
    auto COMPUTE = [&](int buf) {
        bf16x8 af[4], bfr[4];
#pragma unroll
        for (int m = 0; m < 4; m++)
            af[m] = *(const bf16x8*)&lds_a[buf * 4096 + (wr * 64 + m * 16 + fr) * 32 + kg * 8];
#pragma unroll
        for (int n = 0; n < 4; n++)
            bfr[n] = *(const bf16x8*)&lds_b[buf * 8192 + (wn * 64 + n * 16 + fr) * 32 + kg * 8];
#pragma unroll
        for (int m = 0; m < 4; m++)
#pragma unroll
            for (int n = 0; n < 4; n++) acc[m][n] = mfma16(af[m], bfr[n], acc[m][n]);
    };

    STAGE(0, 0);
    STAGE(1, 32);
    int bc = 0, bs = 2;
    for (int s = 0; s < 7; ++s) {
        asm volatile("s_waitcnt vmcnt(3)" ::: "memory");
        __builtin_amdgcn_s_barrier();
        const int k2 = (s + 2) << 5;
        if (k2 < 256) STAGE(bs, k2);
        __builtin_amdgcn_sched_barrier(0);
        COMPUTE(bc);
        bc = (bc == 2) ? 0 : bc + 1;
        bs = (bs == 2) ? 0 : bs + 1;
    }
    asm volatile("s_waitcnt vmcnt(0)" ::: "memory");
    __builtin_amdgcn_s_barrier();
    COMPUTE(bc);

    float bv[4], gv[4], betav[4];
#pragma unroll
    for (int n = 0; n < 4; n++) {
        int col = wn * 64 + n * 16 + fr;
        bv[n] = bias[col];
        gv[n] = g[col];
        betav[n] = b[col];
    }
#pragma unroll
    for (int m = 0; m < 4; m++) {
#pragma unroll
        for (int r = 0; r < 4; r++) {
            float s = 0.f, q2 = 0.f;
#pragma unroll
            for (int n = 0; n < 4; n++) {
                float z = acc[m][n][r] + bv[n];
                s += z;
                q2 += z * z;
            }
#pragma unroll
            for (int off = 1; off < 16; off <<= 1) {
                s += __shfl_xor(s, off);
                q2 += __shfl_xor(q2, off);
            }
            if (fr == 0) {
                int rl = wr * 64 + m * 16 + kg * 4 + r;
                red_s[rl][wn] = s;
                red_q[rl][wn] = q2;
            }
        }
    }
    __syncthreads();
#pragma unroll
    for (int m = 0; m < 4; m++) {
#pragma unroll
        for (int r = 0; r < 4; r++) {
            const int rl = wr * 64 + m * 16 + kg * 4 + r;
            const long rr = row0 + rl;
            float S = red_s[rl][0] + red_s[rl][1] + red_s[rl][2] + red_s[rl][3];
            float Q = red_q[rl][0] + red_q[rl][1] + red_q[rl][2] + red_q[rl][3];
            float mean = S * (1.f / 256.f);
            float var = Q * (1.f / 256.f) - mean * mean;
            float inv = rsqrtf(var + 1e-5f);
            if (rr < M) {
#pragma unroll
                for (int n = 0; n < 4; n++) {
                    int col = wn * 64 + n * 16 + fr;
                    float z = acc[m][n][r] + bv[n];
                    long idx = rr * 256 + col;
                    float o = bf2f(hb[idx]) + fmaxf((z - mean) * inv * gv[n] + betav[n], 0.f);
                    hb[idx] = f2bf(o);
                }
            }
        }
    }
}

// ---------------- host orchestration ----------------
extern "C" void kernel_launch(void* const* d_in, const int* in_sizes, int n_in,
                              void* d_out, int out_size, void* d_ws, size_t ws_size,
                              hipStream_t stream) {
    const float* x    = (const float*)d_in[0];
    const int*   eidx = (const int*)d_in[1];
    const float* ln_g = (const float*)d_in[2];
    const float* ln_b = (const float*)d_in[3];
    const float* W1   = (const float*)d_in[4];
    const float* b1   = (const float*)d_in[5];
    const float* W2   = (const float*)d_in[6];
    const float* b2   = (const float*)d_in[7];
    const float* Wa   = (const float*)d_in[8];
    const float* ba   = (const float*)d_in[9];
    const float* Wb   = (const float*)d_in[10];
    const float* bb   = (const float*)d_in[11];
    const float* ng   = (const float*)d_in[12];
    const float* nbt  = (const float*)d_in[13];
    const float* Wd1  = (const float*)d_in[14];
    const float* bd1  = (const float*)d_in[15];
    const float* Wd2  = (const float*)d_in[16];
    const float* bd2  = (const float*)d_in[17];
    const float* outg = (const float*)d_in[18];
    const float* outbeta = (const float*)d_in[19];
    float* out = (float*)d_out;

    const int N = in_sizes[0] / 1024;  // 50000
    const int E = in_sizes[1] / 2;     // 800000
    const int* e_src = eidx;
    const int* e_dst = eidx + E;

    char* ws = (char*)d_ws;
    size_t off = 0;
    auto alloc = [&](size_t bytes) -> char* {
        char* p = ws + off;
        off += (bytes + 255) & ~(size_t)255;
        return p;
    };

    unsigned short* xln = (unsigned short*)alloc((size_t)N * 1024 * 2);
    unsigned short* zb16 = xln;                                          // N*256 bf16
    unsigned short* za   = (unsigned short*)((char*)xln + (size_t)N * 256 * 2);  // N*256 bf16
    unsigned short* delta = xln;                                         // N*1024 bf16

    unsigned short* h1 = (unsigned short*)alloc((size_t)N * 512 * 2);    // also d1
    unsigned short* hb = (unsigned short*)alloc((size_t)N * 256 * 2);

    unsigned short* W1T  = (unsigned short*)alloc((size_t)512 * 1024 * 2);
    unsigned short* W2T  = (unsigned short*)alloc((size_t)256 * 512 * 2);
    unsigned short* WaT  = (unsigned short*)alloc((size_t)3 * 256 * 256 * 2);
    unsigned short* WbT  = (unsigned short*)alloc((size_t)3 * 256 * 256 * 2);
    unsigned short* Wd1T = (unsigned short*)alloc((size_t)512 * 256 * 2);
    unsigned short* Wd2T = (unsigned short*)alloc((size_t)1024 * 512 * 2);

    int* deg  = (int*)alloc((size_t)(N + 1) * 4);
    int* rp   = (int*)alloc((size_t)(N + 1) * 4);
    int* cur  = (int*)alloc((size_t)N * 4);
    int* bsum = (int*)alloc(64 * 4);
    int* boff = (int*)alloc(64 * 4);
    int* esrc = (int*)alloc((size_t)E * 4);

    auto cdiv = [](long a, long b) { return (int)((a + b - 1) / b); };

    k_transpose_all<<<6656, 256, 0, stream>>>(W1, W2, Wa, Wb, Wd1, Wd2,
                                              W1T, W2T, WaT, WbT, Wd1T, Wd2T);

    k_zero_i32<<<cdiv(N, 256), 256, 0, stream>>>(deg, N);
    k_hist<<<cdiv(E, 256), 256, 0, stream>>>(e_dst, E, deg);
    int nb1 = cdiv(N, 1024);  // 49
    k_scan1<<<nb1, 1024, 0, stream>>>(deg, rp, bsum, N);
    k_scan2<<<1, 64, 0, stream>>>(bsum, boff, nb1);
    k_scan3<<<cdiv(N, 256), 256, 0, stream>>>(rp, boff, cur, N, E);
    k_fill<<<cdiv(E, 256), 256, 0, stream>>>(e_src, e_dst, E, cur, esrc);

    const int ntM = cdiv(N, 128);   // 391
    const int ntM2 = cdiv(N, 256);  // 196

    // in_proj: W1 and W2 on big 256x256 kernel (K>=512 regime, validated on Wd2)
    k_ln1024_in<<<N, 256, 0, stream>>>(x, ln_g, ln_b, xln);
    k_gemm_big<1, 256><<<ntM2 * 2, 512, 0, stream>>>(xln, W1T, b1, N, 1024, 512, h1);
    k_gemm_big<0, 256><<<ntM2 * 1, 512, 0, stream>>>(h1, W2T, b2, N, 512, 256, hb);

    // GNN blocks (K=256 shapes stay on k_gemm / fused kernel)
    for (int i = 0; i < 3; i++) {
        k_agg<<<cdiv(N, 4), 256, 0, stream>>>(hb, rp, esrc, zb16, N);
        k_gemm<1, 1, 0><<<ntM * 2, 256, 0, stream>>>(zb16, WaT + (size_t)i * 65536, ba + (size_t)i * 256,
                                                     N, 256, 256, za, nullptr);
        k_gemm_fused_ln<<<ntM, 512, 0, stream>>>(za, WbT + (size_t)i * 65536, bb + (size_t)i * 256,
                                                 ng + (size_t)i * 256, nbt + (size_t)i * 256,
                                                 hb, N);
    }

    // delta_proj + output LN
    k_gemm<1, 1, 0><<<ntM * 4, 256, 0, stream>>>(hb, Wd1T, bd1, N, 256, 512, h1, nullptr);
    k_gemm_big<0, 256><<<ntM2 * 4, 512, 0, stream>>>(h1, Wd2T, bd2, N, 512, 1024, delta);
    k_ln1024_out<<<N, 256, 0, stream>>>(x, delta, outg, outbeta, out);
}